// Round 21
// baseline (355.932 us; speedup 1.0000x reference)
//
#include <hip/hip_runtime.h>
#include <hip/hip_bf16.h>

// Problem constants: B=16, N=4096, C=384, M=16, NH=8, HD=48, H=W=64
#define SCALE 0.14433756729740643f  // 48^-0.5

typedef __attribute__((ext_vector_type(8))) short bf16x8;
typedef __attribute__((ext_vector_type(4))) float f32x4;

template <typename T> __device__ inline T cvt_from_f(float v);
template <> __device__ inline float cvt_from_f<float>(float v) { return v; }
template <> __device__ inline __hip_bfloat16 cvt_from_f<__hip_bfloat16>(float v) { return __float2bfloat16(v); }

__device__ inline void gload16(const void* g, void* l) {
  __builtin_amdgcn_global_load_lds((const __attribute__((address_space(1))) void*)g,
                                   (__attribute__((address_space(3))) void*)l, 16, 0, 0);
}

// XCD-bijective swizzle (nwg must be %8==0).
__device__ inline int xcd_flat(int nwg) {
  int flat = (blockIdx.z * gridDim.y + blockIdx.y) * gridDim.x + blockIdx.x;
  int per = nwg >> 3;
  return (flat & 7) * per + (flat >> 3);
}

// ---------------------------------------------------------------------------
// prep: xb = bf16(x); sal[row] = sigmoid(x·wsal + b). One wave per row.
// ---------------------------------------------------------------------------
__global__ __launch_bounds__(256) void prep(const float* __restrict__ x,
                                            const float* __restrict__ wsal,
                                            const float* __restrict__ bsal,
                                            __hip_bfloat16* __restrict__ xb,
                                            float* __restrict__ sal) {
  int wave = threadIdx.x >> 6, lane = threadIdx.x & 63;
  size_t row = (size_t)blockIdx.x * 4 + wave;
  const float* xr = x + row * 384;
  float xs[6];
  float part = 0.f;
#pragma unroll
  for (int j = 0; j < 6; j++) {
    int c = lane + 64 * j;
    xs[j] = xr[c];
    part += xs[j] * wsal[c];
  }
#pragma unroll
  for (int off = 32; off >= 1; off >>= 1) part += __shfl_xor(part, off);
  float s = 1.f / (1.f + __expf(-(part + bsal[0])));
#pragma unroll
  for (int j = 0; j < 6; j++) {
    int c = lane + 64 * j;
    xb[row * 384 + c] = __float2bfloat16(xs[j]);
  }
  if (lane == 0) sal[row] = s;
}

// ---------------------------------------------------------------------------
// xtrans: xbT[b][c][n] = xb[b*4096+n][c]. LDS 64x64 tile transpose.
// Grid (64 n-tiles, 6 c-tiles, 16 b).
// ---------------------------------------------------------------------------
__global__ __launch_bounds__(256) void xtrans(const __hip_bfloat16* __restrict__ xb,
                                              __hip_bfloat16* __restrict__ xbT) {
  __shared__ short t[64][66];
  int n0 = blockIdx.x * 64, c0 = blockIdx.y * 64, b = blockIdx.z;
  int tid = threadIdx.x;
  int r = tid >> 3, c8 = tid & 7;  // r 0..31
#pragma unroll
  for (int i = 0; i < 2; i++) {
    int row = r + i * 32;
    bf16x8 v = *(const bf16x8*)(xb + ((size_t)(b * 4096 + n0 + row)) * 384 + c0 + c8 * 8);
    unsigned int* trow = (unsigned int*)&t[row][c8 * 8];
#pragma unroll
    for (int j = 0; j < 4; j++) {
      union { unsigned int u; short s[2]; } p;
      p.s[0] = v[j * 2];
      p.s[1] = v[j * 2 + 1];
      trow[j] = p.u;
    }
  }
  __syncthreads();
#pragma unroll
  for (int i = 0; i < 2; i++) {
    int crow = r + i * 32;
    short tb[8];
#pragma unroll
    for (int j = 0; j < 8; j++) tb[j] = t[c8 * 8 + j][crow];
    *(ulonglong2*)(xbT + ((size_t)b * 384 + c0 + crow) * 4096 + n0 + c8 * 8) = *(ulonglong2*)tb;
  }
}

// ---------------------------------------------------------------------------
// weights_prep: merged independent weight-prep work, block-uniform dispatch.
//  blocks [0,576):   wvlT[n][k] = bf16(w_kv_agg[k][384+n])
//  blocks [576,720): bt2 upper half = w_proj^T replicated (LDS transpose)
//  blocks [720,728): h = bx-720: qseed slice (in LDS) -> Wl rows for head h
// ---------------------------------------------------------------------------
__global__ __launch_bounds__(256) void weights_prep(const float* __restrict__ wkv,
                                                    const float* __restrict__ wproj,
                                                    const float* __restrict__ seeds,
                                                    const float* __restrict__ wqagg,
                                                    __hip_bfloat16* __restrict__ wvlT,
                                                    __hip_bfloat16* __restrict__ bt2) {
  __shared__ float shbuf[16 * 385];  // reused per branch
  __shared__ float qsl[16][48];
  int bx = blockIdx.x;
  int tid = threadIdx.x;
  if (bx < 576) {
    int idx = bx * 256 + tid;
    if (idx < 384 * 384) {
      int n = idx / 384, k = idx % 384;
      wvlT[idx] = __float2bfloat16(wkv[(size_t)k * 768 + 384 + n]);
    }
  } else if (bx < 720) {
    int bx2 = bx - 576;
    int xt = bx2 % 6, yt = (bx2 / 6) % 6, zb = bx2 / 36;
    float(*t)[65] = (float(*)[65])shbuf;  // [64][65] = 4160 floats < 6160
    int kt = xt * 64, ct = yt * 64;
    int c = tid & 63, r4 = tid >> 6;
#pragma unroll
    for (int i = 0; i < 16; i++) {
      int r = i * 4 + r4;
      t[r][c] = wproj[(size_t)(kt + r) * 384 + ct + c];
    }
    __syncthreads();
    __hip_bfloat16 vals[16];
#pragma unroll
    for (int i = 0; i < 16; i++) vals[i] = __float2bfloat16(t[c][i * 4 + r4]);
    for (int b = zb * 4; b < zb * 4 + 4; b++) {
      __hip_bfloat16* dst = bt2 + (size_t)b * 196608;
#pragma unroll
      for (int i = 0; i < 16; i++) {
        int rr = i * 4 + r4;
        dst[(size_t)(ct + rr) * 512 + kt + c] = vals[i];
      }
    }
  } else {
    int h = bx - 720;  // 0..7
    float(*a1)[385] = (float(*)[385])shbuf;
    for (int idx = tid; idx < 6144; idx += 256) a1[idx / 384][idx % 384] = seeds[idx];
    __syncthreads();
    // qsl[m][d] = SCALE * (seeds[m,:] . w_q_agg[:, h*48+d])
    for (int o = tid; o < 768; o += 256) {
      int m = o / 48, d = o - m * 48;
      const float* wp = wqagg + h * 48 + d;
      float acc0 = 0.f, acc1 = 0.f;
      for (int k = 0; k < 384; k += 2) {
        acc0 += a1[m][k] * wp[(size_t)k * 384];
        acc1 += a1[m][k + 1] * wp[(size_t)(k + 1) * 384];
      }
      qsl[m][d] = (acc0 + acc1) * SCALE;
    }
    __syncthreads();
    // Wl[h*16+m][ci] = sum_d wkv[ci][h*48+d] * qsl[m][d]
    for (int idx = tid; idx < 6144; idx += 256) {
      int m = idx / 384, ci = idx - m * 384;
      const float* wp = wkv + (size_t)ci * 768 + h * 48;
      float acc = 0.f;
#pragma unroll
      for (int d = 0; d < 48; d++) acc += wp[d] * qsl[m][d];
      wvlT[384 * 384 + (size_t)(h * 16 + m) * 384 + ci] = __float2bfloat16(acc);
    }
  }
}

// ---------------------------------------------------------------------------
// MFMA GEMM: out[M,Ncols] = A[M,K] @ BT_b[Ncols,K]^T. XCD-swizzled grid.
// ---------------------------------------------------------------------------
template <int K, typename OT, int BSHIFT>
__global__ __launch_bounds__(256) void gemm_mfma(const __hip_bfloat16* __restrict__ A,
                                                 const __hip_bfloat16* __restrict__ BT,
                                                 OT* __restrict__ out, int Ncols,
                                                 size_t btBatchStride) {
  __shared__ __align__(16) __hip_bfloat16 Asl[128][32];
  __shared__ __align__(16) __hip_bfloat16 Bsl[128][32];
  int nf = xcd_flat(gridDim.x * gridDim.y);
  int bX = nf % gridDim.x, bY = nf / gridDim.x;
  int tid = threadIdx.x;
  int lane = tid & 63;
  int w = tid >> 6;
  int wr = w >> 1, wc = w & 1;
  int fr = lane & 15, fq = lane >> 4;
  int rowBase = bY * 128, colBase = bX * 128;
  const __hip_bfloat16* BTb = BT + (size_t)(rowBase >> BSHIFT) * btBatchStride;

  int r1 = tid >> 2, kc1 = tid & 3;
  int r2 = (tid + 256) >> 2;

  char* aB1 = (char*)Asl + (size_t)(w * 64) * 16;
  char* aB2 = (char*)Asl + (size_t)(256 + w * 64) * 16;
  char* bB1 = (char*)Bsl + (size_t)(w * 64) * 16;
  char* bB2 = (char*)Bsl + (size_t)(256 + w * 64) * 16;

  const __hip_bfloat16* a1 = A + (size_t)(rowBase + r1) * K + kc1 * 8;
  const __hip_bfloat16* a2 = A + (size_t)(rowBase + r2) * K + kc1 * 8;
  const __hip_bfloat16* b1 = BTb + (size_t)(colBase + r1) * K + kc1 * 8;
  const __hip_bfloat16* b2 = BTb + (size_t)(colBase + r2) * K + kc1 * 8;

  f32x4 acc[4][4] = {};

  for (int kk = 0; kk < K; kk += 32) {
    gload16(a1 + kk, aB1);
    gload16(a2 + kk, aB2);
    gload16(b1 + kk, bB1);
    gload16(b2 + kk, bB2);
    __syncthreads();
    bf16x8 af[4], bfv[4];
#pragma unroll
    for (int m = 0; m < 4; m++) af[m] = *(const bf16x8*)&Asl[wr * 64 + m * 16 + fr][fq * 8];
#pragma unroll
    for (int n = 0; n < 4; n++) bfv[n] = *(const bf16x8*)&Bsl[wc * 64 + n * 16 + fr][fq * 8];
#pragma unroll
    for (int m = 0; m < 4; m++)
#pragma unroll
      for (int n = 0; n < 4; n++)
        acc[m][n] = __builtin_amdgcn_mfma_f32_16x16x32_bf16(af[m], bfv[n], acc[m][n], 0, 0, 0);
    __syncthreads();
  }

#pragma unroll
  for (int m = 0; m < 4; m++) {
    int row0 = rowBase + wr * 64 + m * 16 + fq * 4;
#pragma unroll
    for (int n = 0; n < 4; n++) {
      int col = colBase + wc * 64 + n * 16 + fr;
      f32x4 v = acc[m][n];
#pragma unroll
      for (int r = 0; r < 4; r++) out[(size_t)(row0 + r) * Ncols + col] = cvt_from_f<OT>(v[r]);
    }
  }
}

// ---------------------------------------------------------------------------
// gemm_out: final projection, K=512, BK=64, XOR-swizzled LDS (chunk ^= row&7).
// out[65536,384] f32 = A2 @ bt2_b^T. Grid (3, 512), XCD-swizzled.
// ---------------------------------------------------------------------------
__global__ __launch_bounds__(256) void gemm_out(const __hip_bfloat16* __restrict__ A,
                                                const __hip_bfloat16* __restrict__ BT,
                                                float* __restrict__ out) {
  __shared__ __align__(16) __hip_bfloat16 Asl[128][64];
  __shared__ __align__(16) __hip_bfloat16 Bsl[128][64];
  int nf = xcd_flat(1536);
  int bX = nf % 3, bY = nf / 3;
  int tid = threadIdx.x;
  int lane = tid & 63;
  int w = tid >> 6;
  int wr = w >> 1, wc = w & 1;
  int fr = lane & 15, fq = lane >> 4;
  int rowBase = bY * 128, colBase = bX * 128;
  const __hip_bfloat16* BTb = BT + (size_t)(rowBase >> 12) * (384 * 512);

  int r0 = tid >> 3, jc = tid & 7;
  int kc = jc ^ (r0 & 7);
  char* aB[4];
  char* bB[4];
  const __hip_bfloat16* a_src[4];
  const __hip_bfloat16* b_src[4];
#pragma unroll
  for (int i = 0; i < 4; i++) {
    aB[i] = (char*)Asl + (size_t)(i * 256 + w * 64) * 16;
    bB[i] = (char*)Bsl + (size_t)(i * 256 + w * 64) * 16;
    a_src[i] = A + (size_t)(rowBase + r0 + i * 32) * 512 + kc * 8;
    b_src[i] = BTb + (size_t)(colBase + r0 + i * 32) * 512 + kc * 8;
  }

  f32x4 acc[4][4] = {};

  for (int kk = 0; kk < 512; kk += 64) {
#pragma unroll
    for (int i = 0; i < 4; i++) {
      gload16(a_src[i] + kk, aB[i]);
      gload16(b_src[i] + kk, bB[i]);
    }
    __syncthreads();
#pragma unroll
    for (int half = 0; half < 2; half++) {
      bf16x8 af[4], bfv[4];
#pragma unroll
      for (int m = 0; m < 4; m++) {
        int row = wr * 64 + m * 16 + fr;
        af[m] = *(const bf16x8*)((char*)Asl + (size_t)row * 128 +
                                 (((fq + 4 * half) ^ (row & 7)) << 4));
      }
#pragma unroll
      for (int n = 0; n < 4; n++) {
        int row = wc * 64 + n * 16 + fr;
        bfv[n] = *(const bf16x8*)((char*)Bsl + (size_t)row * 128 +
                                  (((fq + 4 * half) ^ (row & 7)) << 4));
      }
#pragma unroll
      for (int m = 0; m < 4; m++)
#pragma unroll
        for (int n = 0; n < 4; n++)
          acc[m][n] = __builtin_amdgcn_mfma_f32_16x16x32_bf16(af[m], bfv[n], acc[m][n], 0, 0, 0);
    }
    __syncthreads();
  }

#pragma unroll
  for (int m = 0; m < 4; m++) {
    int row0 = rowBase + wr * 64 + m * 16 + fq * 4;
#pragma unroll
    for (int n = 0; n < 4; n++) {
      int col = colBase + wc * 64 + n * 16 + fr;
      f32x4 v = acc[m][n];
#pragma unroll
      for (int r = 0; r < 4; r++) out[(size_t)(row0 + r) * 384 + col] = v[r];
    }
  }
}

// ---------------------------------------------------------------------------
// gemm_logits: BK=64 swizzled. lgT[b*128+hm][n] = sal·(xb @ Wl^T), transposed
// bf16 write. BT = Wl[128][384]. Grid (512).
// ---------------------------------------------------------------------------
__global__ __launch_bounds__(256) void gemm_logits(const __hip_bfloat16* __restrict__ A,
                                                   const __hip_bfloat16* __restrict__ BT,
                                                   __hip_bfloat16* __restrict__ lgT,
                                                   const float* __restrict__ rowScale) {
  __shared__ __align__(16) __hip_bfloat16 Asl[128][64];
  __shared__ __align__(16) __hip_bfloat16 Bsl[128][64];
  int tid = threadIdx.x;
  int lane = tid & 63;
  int w = tid >> 6;
  int wr = w >> 1, wc = w & 1;
  int fr = lane & 15, fq = lane >> 4;
  int rowBase = blockIdx.x * 128;

  int r0 = tid >> 3, jc = tid & 7;
  int kc = jc ^ (r0 & 7);
  char* aB[4];
  char* bB[4];
  const __hip_bfloat16* a_src[4];
  const __hip_bfloat16* b_src[4];
#pragma unroll
  for (int i = 0; i < 4; i++) {
    aB[i] = (char*)Asl + (size_t)(i * 256 + w * 64) * 16;
    bB[i] = (char*)Bsl + (size_t)(i * 256 + w * 64) * 16;
    a_src[i] = A + (size_t)(rowBase + r0 + i * 32) * 384 + kc * 8;
    b_src[i] = BT + (size_t)(r0 + i * 32) * 384 + kc * 8;
  }

  f32x4 acc[4][4] = {};

  for (int kk = 0; kk < 384; kk += 64) {
#pragma unroll
    for (int i = 0; i < 4; i++) {
      gload16(a_src[i] + kk, aB[i]);
      gload16(b_src[i] + kk, bB[i]);
    }
    __syncthreads();
#pragma unroll
    for (int half = 0; half < 2; half++) {
      bf16x8 af[4], bfv[4];
#pragma unroll
      for (int m = 0; m < 4; m++) {
        int row = wr * 64 + m * 16 + fr;
        af[m] = *(const bf16x8*)((char*)Asl + (size_t)row * 128 +
                                 (((fq + 4 * half) ^ (row & 7)) << 4));
      }
#pragma unroll
      for (int n = 0; n < 4; n++) {
        int row = wc * 64 + n * 16 + fr;
        bfv[n] = *(const bf16x8*)((char*)Bsl + (size_t)row * 128 +
                                  (((fq + 4 * half) ^ (row & 7)) << 4));
      }
#pragma unroll
      for (int m = 0; m < 4; m++)
#pragma unroll
        for (int n = 0; n < 4; n++)
          acc[m][n] = __builtin_amdgcn_mfma_f32_16x16x32_bf16(af[m], bfv[n], acc[m][n], 0, 0, 0);
    }
    __syncthreads();
  }

  float sv[4][4];
#pragma unroll
  for (int m = 0; m < 4; m++)
#pragma unroll
    for (int r = 0; r < 4; r++)
      sv[m][r] = rowScale[rowBase + wr * 64 + m * 16 + fq * 4 + r];

#pragma unroll
  for (int m = 0; m < 4; m++) {
    int row0 = rowBase + wr * 64 + m * 16 + fq * 4;
    int bb = row0 >> 12;
    int n0 = row0 & 4095;
#pragma unroll
    for (int n = 0; n < 4; n++) {
      int col = wc * 64 + n * 16 + fr;  // 0..127 = hm
      __hip_bfloat16 tb[4];
#pragma unroll
      for (int r = 0; r < 4; r++) tb[r] = __float2bfloat16(acc[m][n][r] * sv[m][r]);
      *(unsigned long long*)(lgT + ((size_t)bb * 128 + col) * 4096 + n0) = *(unsigned long long*)tb;
    }
  }
}

// ---------------------------------------------------------------------------
// softmax_rows: Ps[g][n] = softmax_n(lgT[g][n]) * sal[b*4096+n]. bf16 in/out.
// ---------------------------------------------------------------------------
__global__ __launch_bounds__(256) void softmax_rows(const __hip_bfloat16* __restrict__ lgT,
                                                    const float* __restrict__ sal,
                                                    __hip_bfloat16* __restrict__ PT) {
  int g = blockIdx.x;
  const __hip_bfloat16* row = lgT + (size_t)g * 4096;
  int tid = threadIdx.x, wv = tid >> 6, lane = tid & 63;
  __shared__ float redm[4], reds[4];
  float v[16];
  union { ulonglong2 u; __hip_bfloat16 h[8]; } L0, L1;
  L0.u = *(const ulonglong2*)(row + tid * 16);
  L1.u = *(const ulonglong2*)(row + tid * 16 + 8);
#pragma unroll
  for (int i = 0; i < 8; i++) {
    v[i] = __bfloat162float(L0.h[i]);
    v[8 + i] = __bfloat162float(L1.h[i]);
  }
  float mx = v[0];
#pragma unroll
  for (int i = 1; i < 16; i++) mx = fmaxf(mx, v[i]);
#pragma unroll
  for (int off = 1; off < 64; off <<= 1) mx = fmaxf(mx, __shfl_xor(mx, off));
  if (lane == 0) redm[wv] = mx;
  __syncthreads();
  mx = fmaxf(fmaxf(redm[0], redm[1]), fmaxf(redm[2], redm[3]));
  float s = 0.f;
#pragma unroll
  for (int i = 0; i < 16; i++) {
    v[i] = __expf(v[i] - mx);
    s += v[i];
  }
#pragma unroll
  for (int off = 1; off < 64; off <<= 1) s += __shfl_xor(s, off);
  if (lane == 0) reds[wv] = s;
  __syncthreads();
  s = (reds[0] + reds[1]) + (reds[2] + reds[3]);
  float inv = 1.f / s;
  const float* sp = sal + (size_t)(g >> 7) * 4096 + tid * 16;
  float salv[16];
#pragma unroll
  for (int i = 0; i < 4; i++) {
    float4 q = *(const float4*)(sp + i * 4);
    salv[i * 4] = q.x; salv[i * 4 + 1] = q.y; salv[i * 4 + 2] = q.z; salv[i * 4 + 3] = q.w;
  }
  __hip_bfloat16 tb[16];
#pragma unroll
  for (int i = 0; i < 16; i++) tb[i] = __float2bfloat16(v[i] * inv * salv[i]);
  __hip_bfloat16* op = PT + (size_t)g * 4096 + tid * 16;
  *(ulonglong2*)op = *(ulonglong2*)tb;
  *(ulonglong2*)(op + 8) = *(ulonglong2*)(tb + 8);
}

// ---------------------------------------------------------------------------
// gemm_pvx: BK=64 swizzled split-K PV: pbuf[z][g][c] = Ps[g,zslice] @ xbT_b^T.
// Grid (3, 16, 4), XCD-swizzled.
// ---------------------------------------------------------------------------
__global__ __launch_bounds__(256) void gemm_pvx(const __hip_bfloat16* __restrict__ PT,
                                                const __hip_bfloat16* __restrict__ xbT,
                                                float* __restrict__ pbuf) {
  __shared__ __align__(16) __hip_bfloat16 Asl[128][64];
  __shared__ __align__(16) __hip_bfloat16 Bsl[128][64];
  int nf = xcd_flat(192);
  int bX = nf % 3, bY = (nf / 3) & 15, kz = nf / 48;
  int tid = threadIdx.x;
  int lane = tid & 63;
  int w = tid >> 6;
  int wr = w >> 1, wc = w & 1;
  int fr = lane & 15, fq = lane >> 4;
  int rowBase = bY * 128, colBase = bX * 128;
  const __hip_bfloat16* BTb = xbT + (size_t)bY * 384 * 4096;

  int r0 = tid >> 3, jc = tid & 7;
  int kc = jc ^ (r0 & 7);
  char* aB[4];
  char* bB[4];
  const __hip_bfloat16* a_src[4];
  const __hip_bfloat16* b_src[4];
#pragma unroll
  for (int i = 0; i < 4; i++) {
    aB[i] = (char*)Asl + (size_t)(i * 256 + w * 64) * 16;
    bB[i] = (char*)Bsl + (size_t)(i * 256 + w * 64) * 16;
    a_src[i] = PT + (size_t)(rowBase + r0 + i * 32) * 4096 + kz * 1024 + kc * 8;
    b_src[i] = BTb + (size_t)(colBase + r0 + i * 32) * 4096 + kz * 1024 + kc * 8;
  }

  f32x4 acc[4][4] = {};

  for (int kk = 0; kk < 1024; kk += 64) {
#pragma unroll
    for (int i = 0; i < 4; i++) {
      gload16(a_src[i] + kk, aB[i]);
      gload16(b_src[i] + kk, bB[i]);
    }
    __syncthreads();
#pragma unroll
    for (int half = 0; half < 2; half++) {
      bf16x8 af[4], bfv[4];
#pragma unroll
      for (int m = 0; m < 4; m++) {
        int row = wr * 64 + m * 16 + fr;
        af[m] = *(const bf16x8*)((char*)Asl + (size_t)row * 128 +
                                 (((fq + 4 * half) ^ (row & 7)) << 4));
      }
#pragma unroll
      for (int n = 0; n < 4; n++) {
        int row = wc * 64 + n * 16 + fr;
        bfv[n] = *(const bf16x8*)((char*)Bsl + (size_t)row * 128 +
                                  (((fq + 4 * half) ^ (row & 7)) << 4));
      }
#pragma unroll
      for (int m = 0; m < 4; m++)
#pragma unroll
        for (int n = 0; n < 4; n++)
          acc[m][n] = __builtin_amdgcn_mfma_f32_16x16x32_bf16(af[m], bfv[n], acc[m][n], 0, 0, 0);
    }
    __syncthreads();
  }

  float* outz = pbuf + (size_t)kz * 786432;
#pragma unroll
  for (int m = 0; m < 4; m++) {
    int row0 = rowBase + wr * 64 + m * 16 + fq * 4;
#pragma unroll
    for (int n = 0; n < 4; n++) {
      int col = colBase + wc * 64 + n * 16 + fr;
      f32x4 v = acc[m][n];
#pragma unroll
      for (int r = 0; r < 4; r++) outz[(size_t)(row0 + r) * 384 + col] = v[r];
    }
  }
}

// ---------------------------------------------------------------------------
// reduce_z: pvx[i] = bf16(sum_z pbuf[z][i]), 4 elems/thread. Grid 768.
// ---------------------------------------------------------------------------
__global__ __launch_bounds__(256) void reduce_z(const float* __restrict__ pbuf,
                                                __hip_bfloat16* __restrict__ pvx) {
  int i4 = (blockIdx.x * 256 + threadIdx.x) * 4;
  float4 s = *(const float4*)(pbuf + i4);
#pragma unroll
  for (int z = 1; z < 4; z++) {
    float4 t = *(const float4*)(pbuf + (size_t)z * 786432 + i4);
    s.x += t.x; s.y += t.y; s.z += t.z; s.w += t.w;
  }
  __hip_bfloat16 tb[4] = {__float2bfloat16(s.x), __float2bfloat16(s.y),
                          __float2bfloat16(s.z), __float2bfloat16(s.w)};
  *(unsigned long long*)(pvx + i4) = *(unsigned long long*)tb;
}

// ---------------------------------------------------------------------------
// anch_fix: anch1[b][m][c] = seeds[m][c] + outF[b*128 + (c/48)*16 + m][c].
// ---------------------------------------------------------------------------
__global__ void anch_fix(const float* __restrict__ outF, const float* __restrict__ seeds,
                         float* __restrict__ anch1) {
  int idx = blockIdx.x * 256 + threadIdx.x;  // 98304
  int b = idx / 6144;
  int rem = idx - b * 6144;
  int m = rem / 384, c = rem - m * 384;
  int h = c / 48;
  anch1[idx] = seeds[rem] + outF[((size_t)b * 128 + h * 16 + m) * 384 + c];
}

// ---------------------------------------------------------------------------
// kvfold: fused kv_bcast projection + per-batch folded-weight fills.
// Grid (16, 16): x<8 -> wpbT (h=x, k-half, SCALE folded); x>=8 -> bt2 v-half.
// ---------------------------------------------------------------------------
__global__ __launch_bounds__(256) void kvfold(const float* __restrict__ anch2,
                                              const float* __restrict__ wkvb,
                                              const float* __restrict__ wq,
                                              const float* __restrict__ wproj,
                                              __hip_bfloat16* __restrict__ wpbT,
                                              __hip_bfloat16* __restrict__ bt2) {
  int b = blockIdx.y;
  int tid = threadIdx.x;
  __shared__ float a2s[16][385];
  __shared__ float stage[16][48];
  __shared__ __hip_bfloat16 obuf[16][264];
  bool isK = blockIdx.x < 8;
  int h = isK ? blockIdx.x : blockIdx.x - 8;
  int colBase = (isK ? 0 : 384) + h * 48;
  float scale = isK ? SCALE : 1.f;
  for (int idx = tid; idx < 6144; idx += 256) a2s[idx / 384][idx % 384] = anch2[b * 6144 + idx];
  __syncthreads();
  for (int o = tid; o < 768; o += 256) {
    int m = o / 48, d = o - m * 48;
    const float* wp = wkvb + colBase + d;
    float acc0 = 0.f, acc1 = 0.f, acc2 = 0.f, acc3 = 0.f;
#pragma unroll 4
    for (int k = 0; k < 384; k += 4) {
      acc0 += a2s[m][k] * wp[(size_t)k * 768];
      acc1 += a2s[m][k + 1] * wp[(size_t)(k + 1) * 768];
      acc2 += a2s[m][k + 2] * wp[(size_t)(k + 2) * 768];
      acc3 += a2s[m][k + 3] * wp[(size_t)(k + 3) * 768];
    }
    stage[m][d] = ((acc0 + acc1) + (acc2 + acc3)) * scale;
  }
  __syncthreads();
  if (isK) {
    for (int kbase = 0; kbase < 384; kbase += 256) {
      int chunk = (kbase == 0) ? 256 : 128;
      if (tid < chunk) {
        int k = kbase + tid;
        const float4* wp = (const float4*)(wq + (size_t)k * 384 + h * 48);
        float acc[16] = {};
#pragma unroll
        for (int dq = 0; dq < 12; dq++) {
          float4 wv = wp[dq];
#pragma unroll
          for (int m = 0; m < 16; m++)
            acc[m] += stage[m][dq * 4] * wv.x + stage[m][dq * 4 + 1] * wv.y +
                      stage[m][dq * 4 + 2] * wv.z + stage[m][dq * 4 + 3] * wv.w;
        }
#pragma unroll
        for (int m = 0; m < 16; m++) obuf[m][tid] = __float2bfloat16(acc[m]);
      }
      __syncthreads();
      for (int widx = tid; widx < 16 * chunk; widx += 256) {
        int m = widx / chunk, kk = widx - m * chunk;
        wpbT[(size_t)b * 49152 + (size_t)(h * 16 + m) * 384 + kbase + kk] = obuf[m][kk];
      }
      __syncthreads();
    }
  } else {
    for (int cp = tid; cp < 384; cp += 256) {
      float acc[16] = {};
      for (int d = 0; d < 48; d++) {
        float wv = wproj[(size_t)(h * 48 + d) * 384 + cp];
#pragma unroll
        for (int m = 0; m < 16; m++) acc[m] += stage[m][d] * wv;
      }
      __hip_bfloat16 tb[16];
#pragma unroll
      for (int m = 0; m < 16; m++) tb[m] = __float2bfloat16(acc[m]);
      __hip_bfloat16* dst = bt2 + (size_t)b * 196608 + (size_t)cp * 512 + 384 + h * 16;
      *(ulonglong2*)dst = *(ulonglong2*)tb;
      *(ulonglong2*)(dst + 8) = *(ulonglong2*)(tb + 8);
    }
  }
}

// ---------------------------------------------------------------------------
// pgemm: BK=64 swizzled. P = softmax_per_head(xb @ W_pbT_b^T) -> A2[:,384+hm].
// Grid (512).
// ---------------------------------------------------------------------------
__global__ __launch_bounds__(256) void pgemm(const __hip_bfloat16* __restrict__ A,
                                             const __hip_bfloat16* __restrict__ wpbT,
                                             __hip_bfloat16* __restrict__ A2) {
  __shared__ __align__(16) __hip_bfloat16 Asl[128][64];
  __shared__ __align__(16) __hip_bfloat16 Bsl[128][64];
  int tid = threadIdx.x;
  int lane = tid & 63;
  int w = tid >> 6;
  int wr = w >> 1, wc = w & 1;
  int fr = lane & 15, fq = lane >> 4;
  int rowBase = blockIdx.x * 128;
  const __hip_bfloat16* BTb = wpbT + (size_t)(rowBase >> 12) * (128 * 384);

  int r0 = tid >> 3, jc = tid & 7;
  int kc = jc ^ (r0 & 7);
  char* aB[4];
  char* bB[4];
  const __hip_bfloat16* a_src[4];
  const __hip_bfloat16* b_src[4];
#pragma unroll
  for (int i = 0; i < 4; i++) {
    aB[i] = (char*)Asl + (size_t)(i * 256 + w * 64) * 16;
    bB[i] = (char*)Bsl + (size_t)(i * 256 + w * 64) * 16;
    a_src[i] = A + (size_t)(rowBase + r0 + i * 32) * 384 + kc * 8;
    b_src[i] = BTb + (size_t)(r0 + i * 32) * 384 + kc * 8;
  }

  f32x4 acc[4][4] = {};

  for (int kk = 0; kk < 384; kk += 64) {
#pragma unroll
    for (int i = 0; i < 4; i++) {
      gload16(a_src[i] + kk, aB[i]);
      gload16(b_src[i] + kk, bB[i]);
    }
    __syncthreads();
#pragma unroll
    for (int half = 0; half < 2; half++) {
      bf16x8 af[4], bfv[4];
#pragma unroll
      for (int m = 0; m < 4; m++) {
        int row = wr * 64 + m * 16 + fr;
        af[m] = *(const bf16x8*)((char*)Asl + (size_t)row * 128 +
                                 (((fq + 4 * half) ^ (row & 7)) << 4));
      }
#pragma unroll
      for (int n = 0; n < 4; n++) {
        int row = wc * 64 + n * 16 + fr;
        bfv[n] = *(const bf16x8*)((char*)Bsl + (size_t)row * 128 +
                                  (((fq + 4 * half) ^ (row & 7)) << 4));
      }
#pragma unroll
      for (int m = 0; m < 4; m++)
#pragma unroll
        for (int n = 0; n < 4; n++)
          acc[m][n] = __builtin_amdgcn_mfma_f32_16x16x32_bf16(af[m], bfv[n], acc[m][n], 0, 0, 0);
    }
    __syncthreads();
  }

  // epilogue: per (row, head) softmax over the 16-lane fr group -> A2[:,384+col]
#pragma unroll
  for (int m = 0; m < 4; m++) {
    int row0 = rowBase + wr * 64 + m * 16 + fq * 4;
#pragma unroll
    for (int n = 0; n < 4; n++) {
      int col = wc * 64 + n * 16 + fr;
      f32x4 v = acc[m][n];
      f32x4 mx = v;
#pragma unroll
      for (int off = 1; off < 16; off <<= 1)
#pragma unroll
        for (int r = 0; r < 4; r++) mx[r] = fmaxf(mx[r], __shfl_xor(mx[r], off));
      f32x4 e;
#pragma unroll
      for (int r = 0; r < 4; r++) e[r] = __expf(v[r] - mx[r]);
      f32x4 s = e;
#pragma unroll
      for (int off = 1; off < 16; off <<= 1)
#pragma unroll
        for (int r = 0; r < 4; r++) s[r] += __shfl_xor(s[r], off);
#pragma unroll
      for (int r = 0; r < 4; r++)
        A2[(size_t)(row0 + r) * 512 + 384 + col] = __float2bfloat16(e[r] / s[r]);
    }
  }
}

// ---------------------------------------------------------------------------
// dwconv3: depthwise 3x3 conv with x-walking register-rotated tap columns.
// ---------------------------------------------------------------------------
__global__ __launch_bounds__(256) void dwconv3(const __hip_bfloat16* __restrict__ xb,
                                               const float* __restrict__ dwk,
                                               __hip_bfloat16* __restrict__ A2) {
  int b = blockIdx.y;
  int y = blockIdx.x;  // 0..63
  int w = threadIdx.x >> 6, lane = threadIdx.x & 63;
  int c0 = lane * 6;
  int x0 = w * 16;
  float kw[9][6];
#pragma unroll
  for (int ki = 0; ki < 9; ki++)
#pragma unroll
    for (int i = 0; i < 6; i++) kw[ki][i] = dwk[(c0 + i) * 9 + ki];

  const __hip_bfloat16* base = xb + ((size_t)(b * 4096 + y * 64)) * 384 + c0;
  bool yv[3];
#pragma unroll
  for (int t = 0; t < 3; t++) {
    int yy = y + t - 1;
    yv[t] = (yy >= 0 && yy < 64);
  }

  float colL[3][6], colC[3][6], colR[3][6];
  auto loadcol = [&](float (&dst)[3][6], int x) {
#pragma unroll
    for (int t = 0; t < 3; t++) {
      if (yv[t]) {
        const __hip_bfloat16* p = base + ((size_t)(t - 1) * 64 + x) * 384;
#pragma unroll
        for (int i = 0; i < 6; i++) dst[t][i] = __bfloat162float(p[i]);
      } else {
#pragma unroll
        for (int i = 0; i < 6; i++) dst[t][i] = 0.f;
      }
    }
  };

  if (x0 == 0) {
#pragma unroll
    for (int t = 0; t < 3; t++)
#pragma unroll
      for (int i = 0; i < 6; i++) colL[t][i] = 0.f;
  } else {
    loadcol(colL, x0 - 1);
  }
  loadcol(colC, x0);

  for (int step = 0; step < 16; step++) {
    int x = x0 + step;
    if (x + 1 < 64) {
      loadcol(colR, x + 1);
    } else {
#pragma unroll
      for (int t = 0; t < 3; t++)
#pragma unroll
        for (int i = 0; i < 6; i++) colR[t][i] = 0.f;
    }
    float acc[6];
#pragma unroll
    for (int i = 0; i < 6; i++) {
      float a = 0.f;
#pragma unroll
      for (int t = 0; t < 3; t++)
        a += colL[t][i] * kw[t * 3 + 0][i] + colC[t][i] * kw[t * 3 + 1][i] +
             colR[t][i] * kw[t * 3 + 2][i];
      acc[i] = a;
    }
    __hip_bfloat16 tb[6];
#pragma unroll
    for (int i = 0; i < 6; i++) tb[i] = __float2bfloat16(acc[i]);
    __hip_bfloat16* gp = A2 + ((size_t)(b * 4096 + y * 64 + x)) * 512 + c0;
    *(unsigned int*)(gp) = *(unsigned int*)(tb);
    *(unsigned int*)(gp + 2) = *(unsigned int*)(tb + 2);
    *(unsigned int*)(gp + 4) = *(unsigned int*)(tb + 4);
#pragma unroll
    for (int t = 0; t < 3; t++)
#pragma unroll
      for (int i = 0; i < 6; i++) {
        colL[t][i] = colC[t][i];
        colC[t][i] = colR[t][i];
      }
  }
}

// ---------------------------------------------------------------------------
// anchor_proj_qkv: fused q_self (x<24) + kv_self (x>=24) projections.
// ---------------------------------------------------------------------------
__global__ __launch_bounds__(256) void anchor_proj_qkv(const float* __restrict__ A,
                                                       const float* __restrict__ Wq,
                                                       const float* __restrict__ Wkv,
                                                       float* __restrict__ q_out,
                                                       float* __restrict__ kv_out) {
  bool isQ = blockIdx.x < 24;
  int bx = isQ ? blockIdx.x : blockIdx.x - 24;
  const float* W = isQ ? Wq : Wkv;
  float* outp = isQ ? q_out : kv_out;
  int wstride = isQ ? 384 : 768;
  float scale = isQ ? SCALE : 1.f;
  int cs = bx * 16;
  int b = blockIdx.y;
  __shared__ float a1[16][385];
  int tid = threadIdx.x;
  for (int idx = tid; idx < 6144; idx += 256) a1[idx / 384][idx % 384] = A[b * 6144 + idx];
  __syncthreads();
  int m = tid >> 4, cc = tid & 15;
  int col = cs + cc;
  const float* wp = W + col;
  float acc0 = 0.f, acc1 = 0.f, acc2 = 0.f, acc3 = 0.f;
#pragma unroll 4
  for (int k = 0; k < 384; k += 4) {
    acc0 += a1[m][k] * wp[(size_t)k * wstride];
    acc1 += a1[m][k + 1] * wp[(size_t)(k + 1) * wstride];
    acc2 += a1[m][k + 2] * wp[(size_t)(k + 2) * wstride];
    acc3 += a1[m][k + 3] * wp[(size_t)(k + 3) * wstride];
  }
  float acc = ((acc0 + acc1) + (acc2 + acc3)) * scale;
  outp[((size_t)b * 16 + m) * wstride + col] = acc;
}

// ---------------------------------------------------------------------------
// Self attention on anchors (16x16, per (b,h)); anchors2 = anchors1 + out.
// ---------------------------------------------------------------------------
__global__ void self_attn(const float* __restrict__ qsf, const float* __restrict__ kvs,
                          const float* __restrict__ anch1, float* __restrict__ anch2) {
  int h = blockIdx.x & 7, b = blockIdx.x >> 3;
  __shared__ float qs[16][48], ks[16][48], vs[16][48], p[16][17];
  int tid = threadIdx.x;
  for (int idx = tid; idx < 768; idx += 256) {
    int m = idx / 48, d = idx % 48;
    qs[m][d] = qsf[(b * 16 + m) * 384 + h * 48 + d];
    ks[m][d] = kvs[(b * 16 + m) * 768 + h * 48 + d];
    vs[m][d] = kvs[(b * 16 + m) * 768 + 384 + h * 48 + d];
  }
  __syncthreads();
  {
    int mq = tid >> 4, mk = tid & 15;
    float acc = 0.f;
    for (int d = 0; d < 48; d++) acc += qs[mq][d] * ks[mk][d];
    p[mq][mk] = acc;
  }
  __syncthreads();
  if (tid < 16) {
    float mx = -1e30f;
    for (int mk = 0; mk < 16; mk++) mx = fmaxf(mx, p[tid][mk]);
    float sum = 0.f;
    for (int mk = 0; mk < 16; mk++) {
      float e = __expf(p[tid][mk] - mx);
      p[tid][mk] = e;
      sum += e;
    }
    float inv = 1.f / sum;
    for (int mk = 0; mk < 16; mk++) p[tid][mk] *= inv;
  }
  __syncthreads();
  for (int idx = tid; idx < 768; idx += 256) {
    int m = idx / 48, d = idx % 48;
    float acc = 0.f;
    for (int mk = 0; mk < 16; mk++) acc += p[m][mk] * vs[mk][d];
    int c = h * 48 + d;
    anch2[(b * 16 + m) * 384 + c] = anch1[(b * 16 + m) * 384 + c] + acc;
  }
}

// ---------------------------------------------------------------------------
extern "C" void kernel_launch(void* const* d_in, const int* in_sizes, int n_in,
                              void* d_out, int out_size, void* d_ws, size_t ws_size,
                              hipStream_t stream) {
  (void)in_sizes; (void)n_in; (void)out_size; (void)ws_size;
  const float* x = (const float*)d_in[0];
  const float* wsal = (const float*)d_in[3];
  const float* bsal = (const float*)d_in[4];
  const float* seeds = (const float*)d_in[5];
  const float* w_q_agg = (const float*)d_in[6];
  const float* w_kv_agg = (const float*)d_in[7];
  const float* w_q_self = (const float*)d_in[8];
  const float* w_kv_self = (const float*)d_in[9];
  const float* w_q_bcast = (const float*)d_in[10];
  const float* w_kv_bcast = (const float*)d_in[11];
  const float* dwk = (const float*)d_in[12];
  const float* w_proj = (const float*)d_in[13];
  float* out = (float*)d_out;

  char* ws = (char*)d_ws;
  size_t off = 0;
  auto take = [&](size_t bytes) -> void* {
    void* p = ws + off;
    off += (bytes + 255) & ~(size_t)255;
    return p;
  };
  __hip_bfloat16* xb = (__hip_bfloat16*)take(50331648);   // bf16(x)
  __hip_bfloat16* xbT = (__hip_bfloat16*)take(50331648);  // [16][384][4096] bf16
  char* R = (char*)take(67108864);                        // logitsT(16M) -> pbuf(12.6M) -> A2(64M)
  __hip_bfloat16* PT = (__hip_bfloat16*)take(16777216);   // [2048][4096] bf16 (Ps, sal-folded)
  __hip_bfloat16* pvx = (__hip_bfloat16*)take(1572864);   // [2048][384] bf16
  float* outF = (float*)take(3145728);                    // [2048][384] f32
  float* sal = (float*)take(262144);
  float* anch1 = (float*)take(393216);
  float* anch2 = (float*)take(393216);
  float* q_self = (float*)take(393216);
  float* kv_self = (float*)take(786432);
  __hip_bfloat16* wvlT = (__hip_bfloat16*)take(393216);   // [512][384]: wvT ++ Wl
  __hip_bfloat16* wpbT = (__hip_bfloat16*)take(1572864);  // [16][128][384] bf16
  __hip_bfloat16* bt2 = (__hip_bfloat16*)take(6291456);   // [16][384][512] bf16
  __hip_bfloat16* logitsT = (__hip_bfloat16*)R;
  float* pbuf = (float*)R;                  // alias: logits dead after softmax_rows
  __hip_bfloat16* A2 = (__hip_bfloat16*)R;  // alias: pbuf dead after reduce_z

  // 1) xb + saliency; xbT (separate high-occupancy passes)
  prep<<<16384, 256, 0, stream>>>(x, wsal, bsal, xb, sal);
  xtrans<<<dim3(64, 6, 16), 256, 0, stream>>>(xb, xbT);
  // 2) merged weight prep: wvT + bt2 upper half + (qseed->Wl)
  weights_prep<<<728, 256, 0, stream>>>(w_kv_agg, w_proj, seeds, w_q_agg, wvlT, bt2);
  // 3) logits = sal·(xb @ Wl^T), transposed bf16 (BK=64 swizzled)
  gemm_logits<<<512, 256, 0, stream>>>(xb, wvlT + 384 * 384, logitsT, sal);
  // 4) Ps = softmax ⊙ sal; pbuf = Ps @ xbT^T (split-K 4, BK=64 swizzled)
  softmax_rows<<<2048, 256, 0, stream>>>(logitsT, sal, PT);
  gemm_pvx<<<dim3(3, 16, 4), 256, 0, stream>>>(PT, xbT, pbuf);
  reduce_z<<<768, 256, 0, stream>>>(pbuf, pvx);
  // 5) outF = pvx @ wv; anchors1 = seeds + gather(outF)
  gemm_mfma<384, float, 12><<<dim3(3, 16), 256, 0, stream>>>(pvx, wvlT, outF, 384, 0);
  anch_fix<<<384, 256, 0, stream>>>(outF, seeds, anch1);
  // 6) anchor self-attention -> anchors2
  anchor_proj_qkv<<<dim3(72, 16), 256, 0, stream>>>(anch1, w_q_self, w_kv_self, q_self, kv_self);
  self_attn<<<128, 256, 0, stream>>>(q_self, kv_self, anch1, anch2);
  // 7) kv_bcast projection fused with per-batch folded-weight fills
  kvfold<<<dim3(16, 16), 256, 0, stream>>>(anch2, w_kv_bcast, w_q_bcast, w_proj, wpbT, bt2);
  // 8) A2 = [dwconv(xb) | softmax(xb @ W_pbT_b)]  (pbuf dead -> A2, BK=64)
  pgemm<<<512, 256, 0, stream>>>(xb, wpbT, A2);
  dwconv3<<<dim3(64, 16), 256, 0, stream>>>(xb, dwk, A2);
  // 9) out = A2 @ BT2_b   (K=512, BK=64 swizzled, f32 out)
  gemm_out<<<dim3(3, 512), 256, 0, stream>>>(A2, bt2, out);
}

// Round 22
// 319.087 us; speedup vs baseline: 1.1155x; 1.1155x over previous
//
#include <hip/hip_runtime.h>
#include <hip/hip_bf16.h>

// Problem constants: B=16, N=4096, C=384, M=16, NH=8, HD=48, H=W=64
#define SCALE 0.14433756729740643f  // 48^-0.5

typedef __attribute__((ext_vector_type(8))) short bf16x8;
typedef __attribute__((ext_vector_type(4))) float f32x4;

template <typename T> __device__ inline T cvt_from_f(float v);
template <> __device__ inline float cvt_from_f<float>(float v) { return v; }
template <> __device__ inline __hip_bfloat16 cvt_from_f<__hip_bfloat16>(float v) { return __float2bfloat16(v); }

__device__ inline void gload16(const void* g, void* l) {
  __builtin_amdgcn_global_load_lds((const __attribute__((address_space(1))) void*)g,
                                   (__attribute__((address_space(3))) void*)l, 16, 0, 0);
}

// XCD-bijective swizzle (nwg must be %8==0).
__device__ inline int xcd_flat(int nwg) {
  int flat = (blockIdx.z * gridDim.y + blockIdx.y) * gridDim.x + blockIdx.x;
  int per = nwg >> 3;
  return (flat & 7) * per + (flat >> 3);
}

// ---------------------------------------------------------------------------
// prep: xb = bf16(x); sal[row] = sigmoid(x·wsal + b). One wave per row.
// ---------------------------------------------------------------------------
__global__ __launch_bounds__(256) void prep(const float* __restrict__ x,
                                            const float* __restrict__ wsal,
                                            const float* __restrict__ bsal,
                                            __hip_bfloat16* __restrict__ xb,
                                            float* __restrict__ sal) {
  int wave = threadIdx.x >> 6, lane = threadIdx.x & 63;
  size_t row = (size_t)blockIdx.x * 4 + wave;
  const float* xr = x + row * 384;
  float xs[6];
  float part = 0.f;
#pragma unroll
  for (int j = 0; j < 6; j++) {
    int c = lane + 64 * j;
    xs[j] = xr[c];
    part += xs[j] * wsal[c];
  }
#pragma unroll
  for (int off = 32; off >= 1; off >>= 1) part += __shfl_xor(part, off);
  float s = 1.f / (1.f + __expf(-(part + bsal[0])));
#pragma unroll
  for (int j = 0; j < 6; j++) {
    int c = lane + 64 * j;
    xb[row * 384 + c] = __float2bfloat16(xs[j]);
  }
  if (lane == 0) sal[row] = s;
}

// ---------------------------------------------------------------------------
// xtrans: xbT[b][c][n] = xb[b*4096+n][c]. LDS 64x64 tile transpose.
// Grid (64 n-tiles, 6 c-tiles, 16 b).
// ---------------------------------------------------------------------------
__global__ __launch_bounds__(256) void xtrans(const __hip_bfloat16* __restrict__ xb,
                                              __hip_bfloat16* __restrict__ xbT) {
  __shared__ short t[64][66];
  int n0 = blockIdx.x * 64, c0 = blockIdx.y * 64, b = blockIdx.z;
  int tid = threadIdx.x;
  int r = tid >> 3, c8 = tid & 7;  // r 0..31
#pragma unroll
  for (int i = 0; i < 2; i++) {
    int row = r + i * 32;
    bf16x8 v = *(const bf16x8*)(xb + ((size_t)(b * 4096 + n0 + row)) * 384 + c0 + c8 * 8);
    unsigned int* trow = (unsigned int*)&t[row][c8 * 8];
#pragma unroll
    for (int j = 0; j < 4; j++) {
      union { unsigned int u; short s[2]; } p;
      p.s[0] = v[j * 2];
      p.s[1] = v[j * 2 + 1];
      trow[j] = p.u;
    }
  }
  __syncthreads();
#pragma unroll
  for (int i = 0; i < 2; i++) {
    int crow = r + i * 32;
    short tb[8];
#pragma unroll
    for (int j = 0; j < 8; j++) tb[j] = t[c8 * 8 + j][crow];
    *(ulonglong2*)(xbT + ((size_t)b * 384 + c0 + crow) * 4096 + n0 + c8 * 8) = *(ulonglong2*)tb;
  }
}

// ---------------------------------------------------------------------------
// weights_prep: merged independent weight-prep work, block-uniform dispatch.
//  blocks [0,576):   wvlT[n][k] = bf16(w_kv_agg[k][384+n])
//  blocks [576,720): bt2 upper half = w_proj^T replicated (LDS transpose)
//  blocks [720,744): qseed = seeds @ w_q_agg * SCALE (1 col/thread, parallel)
// ---------------------------------------------------------------------------
__global__ __launch_bounds__(256) void weights_prep(const float* __restrict__ wkv,
                                                    const float* __restrict__ wproj,
                                                    const float* __restrict__ seeds,
                                                    const float* __restrict__ wqagg,
                                                    __hip_bfloat16* __restrict__ wvlT,
                                                    __hip_bfloat16* __restrict__ bt2,
                                                    float* __restrict__ qseed) {
  __shared__ float shbuf[16 * 385];  // reused per branch
  int bx = blockIdx.x;
  int tid = threadIdx.x;
  if (bx < 576) {
    int idx = bx * 256 + tid;
    if (idx < 384 * 384) {
      int n = idx / 384, k = idx % 384;
      wvlT[idx] = __float2bfloat16(wkv[(size_t)k * 768 + 384 + n]);
    }
  } else if (bx < 720) {
    int bx2 = bx - 576;
    int xt = bx2 % 6, yt = (bx2 / 6) % 6, zb = bx2 / 36;
    float(*t)[65] = (float(*)[65])shbuf;  // [64][65] = 4160 floats < 6160
    int kt = xt * 64, ct = yt * 64;
    int c = tid & 63, r4 = tid >> 6;
#pragma unroll
    for (int i = 0; i < 16; i++) {
      int r = i * 4 + r4;
      t[r][c] = wproj[(size_t)(kt + r) * 384 + ct + c];
    }
    __syncthreads();
    __hip_bfloat16 vals[16];
#pragma unroll
    for (int i = 0; i < 16; i++) vals[i] = __float2bfloat16(t[c][i * 4 + r4]);
    for (int b = zb * 4; b < zb * 4 + 4; b++) {
      __hip_bfloat16* dst = bt2 + (size_t)b * 196608;
#pragma unroll
      for (int i = 0; i < 16; i++) {
        int rr = i * 4 + r4;
        dst[(size_t)(ct + rr) * 512 + kt + c] = vals[i];
      }
    }
  } else {
    int bxq = bx - 720;  // 0..23
    float(*a1)[385] = (float(*)[385])shbuf;
    int cs = bxq * 16;
    for (int idx = tid; idx < 6144; idx += 256) a1[idx / 384][idx % 384] = seeds[idx];
    __syncthreads();
    int m = tid >> 4, cc = tid & 15;
    int col = cs + cc;
    const float* wp = wqagg + col;
    float acc0 = 0.f, acc1 = 0.f, acc2 = 0.f, acc3 = 0.f;
#pragma unroll 4
    for (int k = 0; k < 384; k += 4) {
      acc0 += a1[m][k] * wp[(size_t)k * 384];
      acc1 += a1[m][k + 1] * wp[(size_t)(k + 1) * 384];
      acc2 += a1[m][k + 2] * wp[(size_t)(k + 2) * 384];
      acc3 += a1[m][k + 3] * wp[(size_t)(k + 3) * 384];
    }
    qseed[m * 384 + col] = ((acc0 + acc1) + (acc2 + acc3)) * SCALE;
  }
}

// ---------------------------------------------------------------------------
// fill_wl: wvlT[384*384 + hm*384 + ci] = sum_d w_kv_agg[ci][h*48+d]*qseed[m][h*48+d].
// Grid 192 (1 output/thread).
// ---------------------------------------------------------------------------
__global__ void fill_wl(const float* __restrict__ wkv, const float* __restrict__ qseed,
                        __hip_bfloat16* __restrict__ wvlT) {
  int idx = blockIdx.x * 256 + threadIdx.x;  // 49152
  int hm = idx / 384, ci = idx - hm * 384;
  int h = hm >> 4, m = hm & 15;
  const float* wp = wkv + (size_t)ci * 768 + h * 48;
  const float* qp = qseed + m * 384 + h * 48;
  float acc = 0.f;
#pragma unroll
  for (int d = 0; d < 48; d++) acc += wp[d] * qp[d];
  wvlT[384 * 384 + idx] = __float2bfloat16(acc);
}

// ---------------------------------------------------------------------------
// MFMA GEMM: out[M,Ncols] = A[M,K] @ BT_b[Ncols,K]^T. XCD-swizzled grid.
// ---------------------------------------------------------------------------
template <int K, typename OT, int BSHIFT>
__global__ __launch_bounds__(256) void gemm_mfma(const __hip_bfloat16* __restrict__ A,
                                                 const __hip_bfloat16* __restrict__ BT,
                                                 OT* __restrict__ out, int Ncols,
                                                 size_t btBatchStride) {
  __shared__ __align__(16) __hip_bfloat16 Asl[128][32];
  __shared__ __align__(16) __hip_bfloat16 Bsl[128][32];
  int nf = xcd_flat(gridDim.x * gridDim.y);
  int bX = nf % gridDim.x, bY = nf / gridDim.x;
  int tid = threadIdx.x;
  int lane = tid & 63;
  int w = tid >> 6;
  int wr = w >> 1, wc = w & 1;
  int fr = lane & 15, fq = lane >> 4;
  int rowBase = bY * 128, colBase = bX * 128;
  const __hip_bfloat16* BTb = BT + (size_t)(rowBase >> BSHIFT) * btBatchStride;

  int r1 = tid >> 2, kc1 = tid & 3;
  int r2 = (tid + 256) >> 2;

  char* aB1 = (char*)Asl + (size_t)(w * 64) * 16;
  char* aB2 = (char*)Asl + (size_t)(256 + w * 64) * 16;
  char* bB1 = (char*)Bsl + (size_t)(w * 64) * 16;
  char* bB2 = (char*)Bsl + (size_t)(256 + w * 64) * 16;

  const __hip_bfloat16* a1 = A + (size_t)(rowBase + r1) * K + kc1 * 8;
  const __hip_bfloat16* a2 = A + (size_t)(rowBase + r2) * K + kc1 * 8;
  const __hip_bfloat16* b1 = BTb + (size_t)(colBase + r1) * K + kc1 * 8;
  const __hip_bfloat16* b2 = BTb + (size_t)(colBase + r2) * K + kc1 * 8;

  f32x4 acc[4][4] = {};

  for (int kk = 0; kk < K; kk += 32) {
    gload16(a1 + kk, aB1);
    gload16(a2 + kk, aB2);
    gload16(b1 + kk, bB1);
    gload16(b2 + kk, bB2);
    __syncthreads();
    bf16x8 af[4], bfv[4];
#pragma unroll
    for (int m = 0; m < 4; m++) af[m] = *(const bf16x8*)&Asl[wr * 64 + m * 16 + fr][fq * 8];
#pragma unroll
    for (int n = 0; n < 4; n++) bfv[n] = *(const bf16x8*)&Bsl[wc * 64 + n * 16 + fr][fq * 8];
#pragma unroll
    for (int m = 0; m < 4; m++)
#pragma unroll
      for (int n = 0; n < 4; n++)
        acc[m][n] = __builtin_amdgcn_mfma_f32_16x16x32_bf16(af[m], bfv[n], acc[m][n], 0, 0, 0);
    __syncthreads();
  }

#pragma unroll
  for (int m = 0; m < 4; m++) {
    int row0 = rowBase + wr * 64 + m * 16 + fq * 4;
#pragma unroll
    for (int n = 0; n < 4; n++) {
      int col = colBase + wc * 64 + n * 16 + fr;
      f32x4 v = acc[m][n];
#pragma unroll
      for (int r = 0; r < 4; r++) out[(size_t)(row0 + r) * Ncols + col] = cvt_from_f<OT>(v[r]);
    }
  }
}

// ---------------------------------------------------------------------------
// gemm_out: final projection, K=512, BK=64, XOR-swizzled LDS (chunk ^= row&7).
// out[65536,384] f32 = A2 @ bt2_b^T. Grid (3, 512), XCD-swizzled.
// ---------------------------------------------------------------------------
__global__ __launch_bounds__(256) void gemm_out(const __hip_bfloat16* __restrict__ A,
                                                const __hip_bfloat16* __restrict__ BT,
                                                float* __restrict__ out) {
  __shared__ __align__(16) __hip_bfloat16 Asl[128][64];
  __shared__ __align__(16) __hip_bfloat16 Bsl[128][64];
  int nf = xcd_flat(1536);
  int bX = nf % 3, bY = nf / 3;
  int tid = threadIdx.x;
  int lane = tid & 63;
  int w = tid >> 6;
  int wr = w >> 1, wc = w & 1;
  int fr = lane & 15, fq = lane >> 4;
  int rowBase = bY * 128, colBase = bX * 128;
  const __hip_bfloat16* BTb = BT + (size_t)(rowBase >> 12) * (384 * 512);

  int r0 = tid >> 3, jc = tid & 7;
  int kc = jc ^ (r0 & 7);
  char* aB[4];
  char* bB[4];
  const __hip_bfloat16* a_src[4];
  const __hip_bfloat16* b_src[4];
#pragma unroll
  for (int i = 0; i < 4; i++) {
    aB[i] = (char*)Asl + (size_t)(i * 256 + w * 64) * 16;
    bB[i] = (char*)Bsl + (size_t)(i * 256 + w * 64) * 16;
    a_src[i] = A + (size_t)(rowBase + r0 + i * 32) * 512 + kc * 8;
    b_src[i] = BTb + (size_t)(colBase + r0 + i * 32) * 512 + kc * 8;
  }

  f32x4 acc[4][4] = {};

  for (int kk = 0; kk < 512; kk += 64) {
#pragma unroll
    for (int i = 0; i < 4; i++) {
      gload16(a_src[i] + kk, aB[i]);
      gload16(b_src[i] + kk, bB[i]);
    }
    __syncthreads();
#pragma unroll
    for (int half = 0; half < 2; half++) {
      bf16x8 af[4], bfv[4];
#pragma unroll
      for (int m = 0; m < 4; m++) {
        int row = wr * 64 + m * 16 + fr;
        af[m] = *(const bf16x8*)((char*)Asl + (size_t)row * 128 +
                                 (((fq + 4 * half) ^ (row & 7)) << 4));
      }
#pragma unroll
      for (int n = 0; n < 4; n++) {
        int row = wc * 64 + n * 16 + fr;
        bfv[n] = *(const bf16x8*)((char*)Bsl + (size_t)row * 128 +
                                  (((fq + 4 * half) ^ (row & 7)) << 4));
      }
#pragma unroll
      for (int m = 0; m < 4; m++)
#pragma unroll
        for (int n = 0; n < 4; n++)
          acc[m][n] = __builtin_amdgcn_mfma_f32_16x16x32_bf16(af[m], bfv[n], acc[m][n], 0, 0, 0);
    }
    __syncthreads();
  }

#pragma unroll
  for (int m = 0; m < 4; m++) {
    int row0 = rowBase + wr * 64 + m * 16 + fq * 4;
#pragma unroll
    for (int n = 0; n < 4; n++) {
      int col = colBase + wc * 64 + n * 16 + fr;
      f32x4 v = acc[m][n];
#pragma unroll
      for (int r = 0; r < 4; r++) out[(size_t)(row0 + r) * 384 + col] = v[r];
    }
  }
}

// ---------------------------------------------------------------------------
// gemm_logits: BK=64 swizzled. lgT[b*128+hm][n] = sal·(xb @ Wl^T), transposed
// bf16 write. BT = Wl[128][384]. Grid (512).
// ---------------------------------------------------------------------------
__global__ __launch_bounds__(256) void gemm_logits(const __hip_bfloat16* __restrict__ A,
                                                   const __hip_bfloat16* __restrict__ BT,
                                                   __hip_bfloat16* __restrict__ lgT,
                                                   const float* __restrict__ rowScale) {
  __shared__ __align__(16) __hip_bfloat16 Asl[128][64];
  __shared__ __align__(16) __hip_bfloat16 Bsl[128][64];
  int tid = threadIdx.x;
  int lane = tid & 63;
  int w = tid >> 6;
  int wr = w >> 1, wc = w & 1;
  int fr = lane & 15, fq = lane >> 4;
  int rowBase = blockIdx.x * 128;

  int r0 = tid >> 3, jc = tid & 7;
  int kc = jc ^ (r0 & 7);
  char* aB[4];
  char* bB[4];
  const __hip_bfloat16* a_src[4];
  const __hip_bfloat16* b_src[4];
#pragma unroll
  for (int i = 0; i < 4; i++) {
    aB[i] = (char*)Asl + (size_t)(i * 256 + w * 64) * 16;
    bB[i] = (char*)Bsl + (size_t)(i * 256 + w * 64) * 16;
    a_src[i] = A + (size_t)(rowBase + r0 + i * 32) * 384 + kc * 8;
    b_src[i] = BT + (size_t)(r0 + i * 32) * 384 + kc * 8;
  }

  f32x4 acc[4][4] = {};

  for (int kk = 0; kk < 384; kk += 64) {
#pragma unroll
    for (int i = 0; i < 4; i++) {
      gload16(a_src[i] + kk, aB[i]);
      gload16(b_src[i] + kk, bB[i]);
    }
    __syncthreads();
#pragma unroll
    for (int half = 0; half < 2; half++) {
      bf16x8 af[4], bfv[4];
#pragma unroll
      for (int m = 0; m < 4; m++) {
        int row = wr * 64 + m * 16 + fr;
        af[m] = *(const bf16x8*)((char*)Asl + (size_t)row * 128 +
                                 (((fq + 4 * half) ^ (row & 7)) << 4));
      }
#pragma unroll
      for (int n = 0; n < 4; n++) {
        int row = wc * 64 + n * 16 + fr;
        bfv[n] = *(const bf16x8*)((char*)Bsl + (size_t)row * 128 +
                                  (((fq + 4 * half) ^ (row & 7)) << 4));
      }
#pragma unroll
      for (int m = 0; m < 4; m++)
#pragma unroll
        for (int n = 0; n < 4; n++)
          acc[m][n] = __builtin_amdgcn_mfma_f32_16x16x32_bf16(af[m], bfv[n], acc[m][n], 0, 0, 0);
    }
    __syncthreads();
  }

  float sv[4][4];
#pragma unroll
  for (int m = 0; m < 4; m++)
#pragma unroll
    for (int r = 0; r < 4; r++)
      sv[m][r] = rowScale[rowBase + wr * 64 + m * 16 + fq * 4 + r];

#pragma unroll
  for (int m = 0; m < 4; m++) {
    int row0 = rowBase + wr * 64 + m * 16 + fq * 4;
    int bb = row0 >> 12;
    int n0 = row0 & 4095;
#pragma unroll
    for (int n = 0; n < 4; n++) {
      int col = wc * 64 + n * 16 + fr;  // 0..127 = hm
      __hip_bfloat16 tb[4];
#pragma unroll
      for (int r = 0; r < 4; r++) tb[r] = __float2bfloat16(acc[m][n][r] * sv[m][r]);
      *(unsigned long long*)(lgT + ((size_t)bb * 128 + col) * 4096 + n0) = *(unsigned long long*)tb;
    }
  }
}

// ---------------------------------------------------------------------------
// softmax_rows: Ps[g][n] = softmax_n(lgT[g][n]) * sal[b*4096+n]. bf16 in/out.
// ---------------------------------------------------------------------------
__global__ __launch_bounds__(256) void softmax_rows(const __hip_bfloat16* __restrict__ lgT,
                                                    const float* __restrict__ sal,
                                                    __hip_bfloat16* __restrict__ PT) {
  int g = blockIdx.x;
  const __hip_bfloat16* row = lgT + (size_t)g * 4096;
  int tid = threadIdx.x, wv = tid >> 6, lane = tid & 63;
  __shared__ float redm[4], reds[4];
  float v[16];
  union { ulonglong2 u; __hip_bfloat16 h[8]; } L0, L1;
  L0.u = *(const ulonglong2*)(row + tid * 16);
  L1.u = *(const ulonglong2*)(row + tid * 16 + 8);
#pragma unroll
  for (int i = 0; i < 8; i++) {
    v[i] = __bfloat162float(L0.h[i]);
    v[8 + i] = __bfloat162float(L1.h[i]);
  }
  float mx = v[0];
#pragma unroll
  for (int i = 1; i < 16; i++) mx = fmaxf(mx, v[i]);
#pragma unroll
  for (int off = 1; off < 64; off <<= 1) mx = fmaxf(mx, __shfl_xor(mx, off));
  if (lane == 0) redm[wv] = mx;
  __syncthreads();
  mx = fmaxf(fmaxf(redm[0], redm[1]), fmaxf(redm[2], redm[3]));
  float s = 0.f;
#pragma unroll
  for (int i = 0; i < 16; i++) {
    v[i] = __expf(v[i] - mx);
    s += v[i];
  }
#pragma unroll
  for (int off = 1; off < 64; off <<= 1) s += __shfl_xor(s, off);
  if (lane == 0) reds[wv] = s;
  __syncthreads();
  s = (reds[0] + reds[1]) + (reds[2] + reds[3]);
  float inv = 1.f / s;
  const float* sp = sal + (size_t)(g >> 7) * 4096 + tid * 16;
  float salv[16];
#pragma unroll
  for (int i = 0; i < 4; i++) {
    float4 q = *(const float4*)(sp + i * 4);
    salv[i * 4] = q.x; salv[i * 4 + 1] = q.y; salv[i * 4 + 2] = q.z; salv[i * 4 + 3] = q.w;
  }
  __hip_bfloat16 tb[16];
#pragma unroll
  for (int i = 0; i < 16; i++) tb[i] = __float2bfloat16(v[i] * inv * salv[i]);
  __hip_bfloat16* op = PT + (size_t)g * 4096 + tid * 16;
  *(ulonglong2*)op = *(ulonglong2*)tb;
  *(ulonglong2*)(op + 8) = *(ulonglong2*)(tb + 8);
}

// ---------------------------------------------------------------------------
// gemm_pvx: BK=64 swizzled split-K PV: pbuf[z][g][c] = Ps[g,zslice] @ xbT_b^T.
// Grid (3, 16, 4), XCD-swizzled.
// ---------------------------------------------------------------------------
__global__ __launch_bounds__(256) void gemm_pvx(const __hip_bfloat16* __restrict__ PT,
                                                const __hip_bfloat16* __restrict__ xbT,
                                                float* __restrict__ pbuf) {
  __shared__ __align__(16) __hip_bfloat16 Asl[128][64];
  __shared__ __align__(16) __hip_bfloat16 Bsl[128][64];
  int nf = xcd_flat(192);
  int bX = nf % 3, bY = (nf / 3) & 15, kz = nf / 48;
  int tid = threadIdx.x;
  int lane = tid & 63;
  int w = tid >> 6;
  int wr = w >> 1, wc = w & 1;
  int fr = lane & 15, fq = lane >> 4;
  int rowBase = bY * 128, colBase = bX * 128;
  const __hip_bfloat16* BTb = xbT + (size_t)bY * 384 * 4096;

  int r0 = tid >> 3, jc = tid & 7;
  int kc = jc ^ (r0 & 7);
  char* aB[4];
  char* bB[4];
  const __hip_bfloat16* a_src[4];
  const __hip_bfloat16* b_src[4];
#pragma unroll
  for (int i = 0; i < 4; i++) {
    aB[i] = (char*)Asl + (size_t)(i * 256 + w * 64) * 16;
    bB[i] = (char*)Bsl + (size_t)(i * 256 + w * 64) * 16;
    a_src[i] = PT + (size_t)(rowBase + r0 + i * 32) * 4096 + kz * 1024 + kc * 8;
    b_src[i] = BTb + (size_t)(colBase + r0 + i * 32) * 4096 + kz * 1024 + kc * 8;
  }

  f32x4 acc[4][4] = {};

  for (int kk = 0; kk < 1024; kk += 64) {
#pragma unroll
    for (int i = 0; i < 4; i++) {
      gload16(a_src[i] + kk, aB[i]);
      gload16(b_src[i] + kk, bB[i]);
    }
    __syncthreads();
#pragma unroll
    for (int half = 0; half < 2; half++) {
      bf16x8 af[4], bfv[4];
#pragma unroll
      for (int m = 0; m < 4; m++) {
        int row = wr * 64 + m * 16 + fr;
        af[m] = *(const bf16x8*)((char*)Asl + (size_t)row * 128 +
                                 (((fq + 4 * half) ^ (row & 7)) << 4));
      }
#pragma unroll
      for (int n = 0; n < 4; n++) {
        int row = wc * 64 + n * 16 + fr;
        bfv[n] = *(const bf16x8*)((char*)Bsl + (size_t)row * 128 +
                                  (((fq + 4 * half) ^ (row & 7)) << 4));
      }
#pragma unroll
      for (int m = 0; m < 4; m++)
#pragma unroll
        for (int n = 0; n < 4; n++)
          acc[m][n] = __builtin_amdgcn_mfma_f32_16x16x32_bf16(af[m], bfv[n], acc[m][n], 0, 0, 0);
    }
    __syncthreads();
  }

  float* outz = pbuf + (size_t)kz * 786432;
#pragma unroll
  for (int m = 0; m < 4; m++) {
    int row0 = rowBase + wr * 64 + m * 16 + fq * 4;
#pragma unroll
    for (int n = 0; n < 4; n++) {
      int col = colBase + wc * 64 + n * 16 + fr;
      f32x4 v = acc[m][n];
#pragma unroll
      for (int r = 0; r < 4; r++) outz[(size_t)(row0 + r) * 384 + col] = v[r];
    }
  }
}

// ---------------------------------------------------------------------------
// reduce_z: pvx[i] = bf16(sum_z pbuf[z][i]), 4 elems/thread. Grid 768.
// ---------------------------------------------------------------------------
__global__ __launch_bounds__(256) void reduce_z(const float* __restrict__ pbuf,
                                                __hip_bfloat16* __restrict__ pvx) {
  int i4 = (blockIdx.x * 256 + threadIdx.x) * 4;
  float4 s = *(const float4*)(pbuf + i4);
#pragma unroll
  for (int z = 1; z < 4; z++) {
    float4 t = *(const float4*)(pbuf + (size_t)z * 786432 + i4);
    s.x += t.x; s.y += t.y; s.z += t.z; s.w += t.w;
  }
  __hip_bfloat16 tb[4] = {__float2bfloat16(s.x), __float2bfloat16(s.y),
                          __float2bfloat16(s.z), __float2bfloat16(s.w)};
  *(unsigned long long*)(pvx + i4) = *(unsigned long long*)tb;
}

// ---------------------------------------------------------------------------
// anch_fix: anch1[b][m][c] = seeds[m][c] + outF[b*128 + (c/48)*16 + m][c].
// ---------------------------------------------------------------------------
__global__ void anch_fix(const float* __restrict__ outF, const float* __restrict__ seeds,
                         float* __restrict__ anch1) {
  int idx = blockIdx.x * 256 + threadIdx.x;  // 98304
  int b = idx / 6144;
  int rem = idx - b * 6144;
  int m = rem / 384, c = rem - m * 384;
  int h = c / 48;
  anch1[idx] = seeds[rem] + outF[((size_t)b * 128 + h * 16 + m) * 384 + c];
}

// ---------------------------------------------------------------------------
// kvfold: fused kv_bcast projection + per-batch folded-weight fills.
// Grid (16, 16): x<8 -> wpbT (h=x, k-half, SCALE folded); x>=8 -> bt2 v-half.
// ---------------------------------------------------------------------------
__global__ __launch_bounds__(256) void kvfold(const float* __restrict__ anch2,
                                              const float* __restrict__ wkvb,
                                              const float* __restrict__ wq,
                                              const float* __restrict__ wproj,
                                              __hip_bfloat16* __restrict__ wpbT,
                                              __hip_bfloat16* __restrict__ bt2) {
  int b = blockIdx.y;
  int tid = threadIdx.x;
  __shared__ float a2s[16][385];
  __shared__ float stage[16][48];
  __shared__ __hip_bfloat16 obuf[16][264];
  bool isK = blockIdx.x < 8;
  int h = isK ? blockIdx.x : blockIdx.x - 8;
  int colBase = (isK ? 0 : 384) + h * 48;
  float scale = isK ? SCALE : 1.f;
  for (int idx = tid; idx < 6144; idx += 256) a2s[idx / 384][idx % 384] = anch2[b * 6144 + idx];
  __syncthreads();
  for (int o = tid; o < 768; o += 256) {
    int m = o / 48, d = o - m * 48;
    const float* wp = wkvb + colBase + d;
    float acc0 = 0.f, acc1 = 0.f, acc2 = 0.f, acc3 = 0.f;
#pragma unroll 4
    for (int k = 0; k < 384; k += 4) {
      acc0 += a2s[m][k] * wp[(size_t)k * 768];
      acc1 += a2s[m][k + 1] * wp[(size_t)(k + 1) * 768];
      acc2 += a2s[m][k + 2] * wp[(size_t)(k + 2) * 768];
      acc3 += a2s[m][k + 3] * wp[(size_t)(k + 3) * 768];
    }
    stage[m][d] = ((acc0 + acc1) + (acc2 + acc3)) * scale;
  }
  __syncthreads();
  if (isK) {
    for (int kbase = 0; kbase < 384; kbase += 256) {
      int chunk = (kbase == 0) ? 256 : 128;
      if (tid < chunk) {
        int k = kbase + tid;
        const float4* wp = (const float4*)(wq + (size_t)k * 384 + h * 48);
        float acc[16] = {};
#pragma unroll
        for (int dq = 0; dq < 12; dq++) {
          float4 wv = wp[dq];
#pragma unroll
          for (int m = 0; m < 16; m++)
            acc[m] += stage[m][dq * 4] * wv.x + stage[m][dq * 4 + 1] * wv.y +
                      stage[m][dq * 4 + 2] * wv.z + stage[m][dq * 4 + 3] * wv.w;
        }
#pragma unroll
        for (int m = 0; m < 16; m++) obuf[m][tid] = __float2bfloat16(acc[m]);
      }
      __syncthreads();
      for (int widx = tid; widx < 16 * chunk; widx += 256) {
        int m = widx / chunk, kk = widx - m * chunk;
        wpbT[(size_t)b * 49152 + (size_t)(h * 16 + m) * 384 + kbase + kk] = obuf[m][kk];
      }
      __syncthreads();
    }
  } else {
    for (int cp = tid; cp < 384; cp += 256) {
      float acc[16] = {};
      for (int d = 0; d < 48; d++) {
        float wv = wproj[(size_t)(h * 48 + d) * 384 + cp];
#pragma unroll
        for (int m = 0; m < 16; m++) acc[m] += stage[m][d] * wv;
      }
      __hip_bfloat16 tb[16];
#pragma unroll
      for (int m = 0; m < 16; m++) tb[m] = __float2bfloat16(acc[m]);
      __hip_bfloat16* dst = bt2 + (size_t)b * 196608 + (size_t)cp * 512 + 384 + h * 16;
      *(ulonglong2*)dst = *(ulonglong2*)tb;
      *(ulonglong2*)(dst + 8) = *(ulonglong2*)(tb + 8);
    }
  }
}

// ---------------------------------------------------------------------------
// pgemm: BK=64 swizzled. P = softmax_per_head(xb @ W_pbT_b^T) -> A2[:,384+hm].
// Grid (512).
// ---------------------------------------------------------------------------
__global__ __launch_bounds__(256) void pgemm(const __hip_bfloat16* __restrict__ A,
                                             const __hip_bfloat16* __restrict__ wpbT,
                                             __hip_bfloat16* __restrict__ A2) {
  __shared__ __align__(16) __hip_bfloat16 Asl[128][64];
  __shared__ __align__(16) __hip_bfloat16 Bsl[128][64];
  int tid = threadIdx.x;
  int lane = tid & 63;
  int w = tid >> 6;
  int wr = w >> 1, wc = w & 1;
  int fr = lane & 15, fq = lane >> 4;
  int rowBase = blockIdx.x * 128;
  const __hip_bfloat16* BTb = wpbT + (size_t)(rowBase >> 12) * (128 * 384);

  int r0 = tid >> 3, jc = tid & 7;
  int kc = jc ^ (r0 & 7);
  char* aB[4];
  char* bB[4];
  const __hip_bfloat16* a_src[4];
  const __hip_bfloat16* b_src[4];
#pragma unroll
  for (int i = 0; i < 4; i++) {
    aB[i] = (char*)Asl + (size_t)(i * 256 + w * 64) * 16;
    bB[i] = (char*)Bsl + (size_t)(i * 256 + w * 64) * 16;
    a_src[i] = A + (size_t)(rowBase + r0 + i * 32) * 384 + kc * 8;
    b_src[i] = BTb + (size_t)(r0 + i * 32) * 384 + kc * 8;
  }

  f32x4 acc[4][4] = {};

  for (int kk = 0; kk < 384; kk += 64) {
#pragma unroll
    for (int i = 0; i < 4; i++) {
      gload16(a_src[i] + kk, aB[i]);
      gload16(b_src[i] + kk, bB[i]);
    }
    __syncthreads();
#pragma unroll
    for (int half = 0; half < 2; half++) {
      bf16x8 af[4], bfv[4];
#pragma unroll
      for (int m = 0; m < 4; m++) {
        int row = wr * 64 + m * 16 + fr;
        af[m] = *(const bf16x8*)((char*)Asl + (size_t)row * 128 +
                                 (((fq + 4 * half) ^ (row & 7)) << 4));
      }
#pragma unroll
      for (int n = 0; n < 4; n++) {
        int row = wc * 64 + n * 16 + fr;
        bfv[n] = *(const bf16x8*)((char*)Bsl + (size_t)row * 128 +
                                  (((fq + 4 * half) ^ (row & 7)) << 4));
      }
#pragma unroll
      for (int m = 0; m < 4; m++)
#pragma unroll
        for (int n = 0; n < 4; n++)
          acc[m][n] = __builtin_amdgcn_mfma_f32_16x16x32_bf16(af[m], bfv[n], acc[m][n], 0, 0, 0);
    }
    __syncthreads();
  }

  // epilogue: per (row, head) softmax over the 16-lane fr group -> A2[:,384+col]
#pragma unroll
  for (int m = 0; m < 4; m++) {
    int row0 = rowBase + wr * 64 + m * 16 + fq * 4;
#pragma unroll
    for (int n = 0; n < 4; n++) {
      int col = wc * 64 + n * 16 + fr;
      f32x4 v = acc[m][n];
      f32x4 mx = v;
#pragma unroll
      for (int off = 1; off < 16; off <<= 1)
#pragma unroll
        for (int r = 0; r < 4; r++) mx[r] = fmaxf(mx[r], __shfl_xor(mx[r], off));
      f32x4 e;
#pragma unroll
      for (int r = 0; r < 4; r++) e[r] = __expf(v[r] - mx[r]);
      f32x4 s = e;
#pragma unroll
      for (int off = 1; off < 16; off <<= 1)
#pragma unroll
        for (int r = 0; r < 4; r++) s[r] += __shfl_xor(s[r], off);
#pragma unroll
      for (int r = 0; r < 4; r++)
        A2[(size_t)(row0 + r) * 512 + 384 + col] = __float2bfloat16(e[r] / s[r]);
    }
  }
}

// ---------------------------------------------------------------------------
// dwconv3: depthwise 3x3 conv with x-walking register-rotated tap columns.
// ---------------------------------------------------------------------------
__global__ __launch_bounds__(256) void dwconv3(const __hip_bfloat16* __restrict__ xb,
                                               const float* __restrict__ dwk,
                                               __hip_bfloat16* __restrict__ A2) {
  int b = blockIdx.y;
  int y = blockIdx.x;  // 0..63
  int w = threadIdx.x >> 6, lane = threadIdx.x & 63;
  int c0 = lane * 6;
  int x0 = w * 16;
  float kw[9][6];
#pragma unroll
  for (int ki = 0; ki < 9; ki++)
#pragma unroll
    for (int i = 0; i < 6; i++) kw[ki][i] = dwk[(c0 + i) * 9 + ki];

  const __hip_bfloat16* base = xb + ((size_t)(b * 4096 + y * 64)) * 384 + c0;
  bool yv[3];
#pragma unroll
  for (int t = 0; t < 3; t++) {
    int yy = y + t - 1;
    yv[t] = (yy >= 0 && yy < 64);
  }

  float colL[3][6], colC[3][6], colR[3][6];
  auto loadcol = [&](float (&dst)[3][6], int x) {
#pragma unroll
    for (int t = 0; t < 3; t++) {
      if (yv[t]) {
        const __hip_bfloat16* p = base + ((size_t)(t - 1) * 64 + x) * 384;
#pragma unroll
        for (int i = 0; i < 6; i++) dst[t][i] = __bfloat162float(p[i]);
      } else {
#pragma unroll
        for (int i = 0; i < 6; i++) dst[t][i] = 0.f;
      }
    }
  };

  if (x0 == 0) {
#pragma unroll
    for (int t = 0; t < 3; t++)
#pragma unroll
      for (int i = 0; i < 6; i++) colL[t][i] = 0.f;
  } else {
    loadcol(colL, x0 - 1);
  }
  loadcol(colC, x0);

  for (int step = 0; step < 16; step++) {
    int x = x0 + step;
    if (x + 1 < 64) {
      loadcol(colR, x + 1);
    } else {
#pragma unroll
      for (int t = 0; t < 3; t++)
#pragma unroll
        for (int i = 0; i < 6; i++) colR[t][i] = 0.f;
    }
    float acc[6];
#pragma unroll
    for (int i = 0; i < 6; i++) {
      float a = 0.f;
#pragma unroll
      for (int t = 0; t < 3; t++)
        a += colL[t][i] * kw[t * 3 + 0][i] + colC[t][i] * kw[t * 3 + 1][i] +
             colR[t][i] * kw[t * 3 + 2][i];
      acc[i] = a;
    }
    __hip_bfloat16 tb[6];
#pragma unroll
    for (int i = 0; i < 6; i++) tb[i] = __float2bfloat16(acc[i]);
    __hip_bfloat16* gp = A2 + ((size_t)(b * 4096 + y * 64 + x)) * 512 + c0;
    *(unsigned int*)(gp) = *(unsigned int*)(tb);
    *(unsigned int*)(gp + 2) = *(unsigned int*)(tb + 2);
    *(unsigned int*)(gp + 4) = *(unsigned int*)(tb + 4);
#pragma unroll
    for (int t = 0; t < 3; t++)
#pragma unroll
      for (int i = 0; i < 6; i++) {
        colL[t][i] = colC[t][i];
        colC[t][i] = colR[t][i];
      }
  }
}

// ---------------------------------------------------------------------------
// anchor_proj_qkv: fused q_self (x<24) + kv_self (x>=24) projections.
// ---------------------------------------------------------------------------
__global__ __launch_bounds__(256) void anchor_proj_qkv(const float* __restrict__ A,
                                                       const float* __restrict__ Wq,
                                                       const float* __restrict__ Wkv,
                                                       float* __restrict__ q_out,
                                                       float* __restrict__ kv_out) {
  bool isQ = blockIdx.x < 24;
  int bx = isQ ? blockIdx.x : blockIdx.x - 24;
  const float* W = isQ ? Wq : Wkv;
  float* outp = isQ ? q_out : kv_out;
  int wstride = isQ ? 384 : 768;
  float scale = isQ ? SCALE : 1.f;
  int cs = bx * 16;
  int b = blockIdx.y;
  __shared__ float a1[16][385];
  int tid = threadIdx.x;
  for (int idx = tid; idx < 6144; idx += 256) a1[idx / 384][idx % 384] = A[b * 6144 + idx];
  __syncthreads();
  int m = tid >> 4, cc = tid & 15;
  int col = cs + cc;
  const float* wp = W + col;
  float acc0 = 0.f, acc1 = 0.f, acc2 = 0.f, acc3 = 0.f;
#pragma unroll 4
  for (int k = 0; k < 384; k += 4) {
    acc0 += a1[m][k] * wp[(size_t)k * wstride];
    acc1 += a1[m][k + 1] * wp[(size_t)(k + 1) * wstride];
    acc2 += a1[m][k + 2] * wp[(size_t)(k + 2) * wstride];
    acc3 += a1[m][k + 3] * wp[(size_t)(k + 3) * wstride];
  }
  float acc = ((acc0 + acc1) + (acc2 + acc3)) * scale;
  outp[((size_t)b * 16 + m) * wstride + col] = acc;
}

// ---------------------------------------------------------------------------
// Self attention on anchors (16x16, per (b,h)); anchors2 = anchors1 + out.
// ---------------------------------------------------------------------------
__global__ void self_attn(const float* __restrict__ qsf, const float* __restrict__ kvs,
                          const float* __restrict__ anch1, float* __restrict__ anch2) {
  int h = blockIdx.x & 7, b = blockIdx.x >> 3;
  __shared__ float qs[16][48], ks[16][48], vs[16][48], p[16][17];
  int tid = threadIdx.x;
  for (int idx = tid; idx < 768; idx += 256) {
    int m = idx / 48, d = idx % 48;
    qs[m][d] = qsf[(b * 16 + m) * 384 + h * 48 + d];
    ks[m][d] = kvs[(b * 16 + m) * 768 + h * 48 + d];
    vs[m][d] = kvs[(b * 16 + m) * 768 + 384 + h * 48 + d];
  }
  __syncthreads();
  {
    int mq = tid >> 4, mk = tid & 15;
    float acc = 0.f;
    for (int d = 0; d < 48; d++) acc += qs[mq][d] * ks[mk][d];
    p[mq][mk] = acc;
  }
  __syncthreads();
  if (tid < 16) {
    float mx = -1e30f;
    for (int mk = 0; mk < 16; mk++) mx = fmaxf(mx, p[tid][mk]);
    float sum = 0.f;
    for (int mk = 0; mk < 16; mk++) {
      float e = __expf(p[tid][mk] - mx);
      p[tid][mk] = e;
      sum += e;
    }
    float inv = 1.f / sum;
    for (int mk = 0; mk < 16; mk++) p[tid][mk] *= inv;
  }
  __syncthreads();
  for (int idx = tid; idx < 768; idx += 256) {
    int m = idx / 48, d = idx % 48;
    float acc = 0.f;
    for (int mk = 0; mk < 16; mk++) acc += p[m][mk] * vs[mk][d];
    int c = h * 48 + d;
    anch2[(b * 16 + m) * 384 + c] = anch1[(b * 16 + m) * 384 + c] + acc;
  }
}

// ---------------------------------------------------------------------------
extern "C" void kernel_launch(void* const* d_in, const int* in_sizes, int n_in,
                              void* d_out, int out_size, void* d_ws, size_t ws_size,
                              hipStream_t stream) {
  (void)in_sizes; (void)n_in; (void)out_size; (void)ws_size;
  const float* x = (const float*)d_in[0];
  const float* wsal = (const float*)d_in[3];
  const float* bsal = (const float*)d_in[4];
  const float* seeds = (const float*)d_in[5];
  const float* w_q_agg = (const float*)d_in[6];
  const float* w_kv_agg = (const float*)d_in[7];
  const float* w_q_self = (const float*)d_in[8];
  const float* w_kv_self = (const float*)d_in[9];
  const float* w_q_bcast = (const float*)d_in[10];
  const float* w_kv_bcast = (const float*)d_in[11];
  const float* dwk = (const float*)d_in[12];
  const float* w_proj = (const float*)d_in[13];
  float* out = (float*)d_out;

  char* ws = (char*)d_ws;
  size_t off = 0;
  auto take = [&](size_t bytes) -> void* {
    void* p = ws + off;
    off += (bytes + 255) & ~(size_t)255;
    return p;
  };
  __hip_bfloat16* xb = (__hip_bfloat16*)take(50331648);   // bf16(x)
  __hip_bfloat16* xbT = (__hip_bfloat16*)take(50331648);  // [16][384][4096] bf16
  char* R = (char*)take(67108864);                        // logitsT(16M) -> pbuf(12.6M) -> A2(64M)
  __hip_bfloat16* PT = (__hip_bfloat16*)take(16777216);   // [2048][4096] bf16 (Ps, sal-folded)
  __hip_bfloat16* pvx = (__hip_bfloat16*)take(1572864);   // [2048][384] bf16
  float* outF = (float*)take(3145728);                    // [2048][384] f32
  float* qseed = (float*)take(24576);
  float* sal = (float*)take(262144);
  float* anch1 = (float*)take(393216);
  float* anch2 = (float*)take(393216);
  float* q_self = (float*)take(393216);
  float* kv_self = (float*)take(786432);
  __hip_bfloat16* wvlT = (__hip_bfloat16*)take(393216);   // [512][384]: wvT ++ Wl
  __hip_bfloat16* wpbT = (__hip_bfloat16*)take(1572864);  // [16][128][384] bf16
  __hip_bfloat16* bt2 = (__hip_bfloat16*)take(6291456);   // [16][384][512] bf16
  __hip_bfloat16* logitsT = (__hip_bfloat16*)R;
  float* pbuf = (float*)R;                  // alias: logits dead after softmax_rows
  __hip_bfloat16* A2 = (__hip_bfloat16*)R;  // alias: pbuf dead after reduce_z

  // 1) xb + saliency; xbT (separate high-occupancy passes)
  prep<<<16384, 256, 0, stream>>>(x, wsal, bsal, xb, sal);
  xtrans<<<dim3(64, 6, 16), 256, 0, stream>>>(xb, xbT);
  // 2) merged weight prep: wvT + bt2 upper half + qseed (parallel)
  weights_prep<<<744, 256, 0, stream>>>(w_kv_agg, w_proj, seeds, w_q_agg, wvlT, bt2, qseed);
  fill_wl<<<192, 256, 0, stream>>>(w_kv_agg, qseed, wvlT);
  // 3) logits = sal·(xb @ Wl^T), transposed bf16 (BK=64 swizzled)
  gemm_logits<<<512, 256, 0, stream>>>(xb, wvlT + 384 * 384, logitsT, sal);
  // 4) Ps = softmax ⊙ sal; pbuf = Ps @ xbT^T (split-K 4, BK=64 swizzled)
  softmax_rows<<<2048, 256, 0, stream>>>(logitsT, sal, PT);
  gemm_pvx<<<dim3(3, 16, 4), 256, 0, stream>>>(PT, xbT, pbuf);
  reduce_z<<<768, 256, 0, stream>>>(pbuf, pvx);
  // 5) outF = pvx @ wv; anchors1 = seeds + gather(outF)
  gemm_mfma<384, float, 12><<<dim3(3, 16), 256, 0, stream>>>(pvx, wvlT, outF, 384, 0);
  anch_fix<<<384, 256, 0, stream>>>(outF, seeds, anch1);
  // 6) anchor self-attention -> anchors2
  anchor_proj_qkv<<<dim3(72, 16), 256, 0, stream>>>(anch1, w_q_self, w_kv_self, q_self, kv_self);
  self_attn<<<128, 256, 0, stream>>>(q_self, kv_self, anch1, anch2);
  // 7) kv_bcast projection fused with per-batch folded-weight fills
  kvfold<<<dim3(16, 16), 256, 0, stream>>>(anch2, w_kv_bcast, w_q_bcast, w_proj, wpbT, bt2);
  // 8) A2 = [dwconv(xb) | softmax(xb @ W_pbT_b)]  (pbuf dead -> A2, BK=64)
  pgemm<<<512, 256, 0, stream>>>(xb, wpbT, A2);
  dwconv3<<<dim3(64, 16), 256, 0, stream>>>(xb, dwk, A2);
  // 9) out = A2 @ BT2_b   (K=512, BK=64 swizzled, f32 out)
  gemm_out<<<dim3(3, 512), 256, 0, stream>>>(A2, bt2, out);
}

// Round 23
// 318.074 us; speedup vs baseline: 1.1190x; 1.0032x over previous
//
#include <hip/hip_runtime.h>
#include <hip/hip_bf16.h>

// Problem constants: B=16, N=4096, C=384, M=16, NH=8, HD=48, H=W=64
#define SCALE 0.14433756729740643f  // 48^-0.5

typedef __attribute__((ext_vector_type(8))) short bf16x8;
typedef __attribute__((ext_vector_type(4))) float f32x4;

__device__ inline void gload16(const void* g, void* l) {
  __builtin_amdgcn_global_load_lds((const __attribute__((address_space(1))) void*)g,
                                   (__attribute__((address_space(3))) void*)l, 16, 0, 0);
}

// XCD-bijective swizzle (nwg must be %8==0).
__device__ inline int xcd_flat(int nwg) {
  int flat = (blockIdx.z * gridDim.y + blockIdx.y) * gridDim.x + blockIdx.x;
  int per = nwg >> 3;
  return (flat & 7) * per + (flat >> 3);
}

// ---------------------------------------------------------------------------
// prep: xb = bf16(x); sal[row] = sigmoid(x·wsal + b). One wave per row.
// ---------------------------------------------------------------------------
__global__ __launch_bounds__(256) void prep(const float* __restrict__ x,
                                            const float* __restrict__ wsal,
                                            const float* __restrict__ bsal,
                                            __hip_bfloat16* __restrict__ xb,
                                            float* __restrict__ sal) {
  int wave = threadIdx.x >> 6, lane = threadIdx.x & 63;
  size_t row = (size_t)blockIdx.x * 4 + wave;
  const float* xr = x + row * 384;
  float xs[6];
  float part = 0.f;
#pragma unroll
  for (int j = 0; j < 6; j++) {
    int c = lane + 64 * j;
    xs[j] = xr[c];
    part += xs[j] * wsal[c];
  }
#pragma unroll
  for (int off = 32; off >= 1; off >>= 1) part += __shfl_xor(part, off);
  float s = 1.f / (1.f + __expf(-(part + bsal[0])));
#pragma unroll
  for (int j = 0; j < 6; j++) {
    int c = lane + 64 * j;
    xb[row * 384 + c] = __float2bfloat16(xs[j]);
  }
  if (lane == 0) sal[row] = s;
}

// ---------------------------------------------------------------------------
// xtrans: xbT[b][c][n] = xb[b*4096+n][c]. LDS 64x64 tile transpose.
// Grid (64 n-tiles, 6 c-tiles, 16 b).
// ---------------------------------------------------------------------------
__global__ __launch_bounds__(256) void xtrans(const __hip_bfloat16* __restrict__ xb,
                                              __hip_bfloat16* __restrict__ xbT) {
  __shared__ short t[64][66];
  int n0 = blockIdx.x * 64, c0 = blockIdx.y * 64, b = blockIdx.z;
  int tid = threadIdx.x;
  int r = tid >> 3, c8 = tid & 7;  // r 0..31
#pragma unroll
  for (int i = 0; i < 2; i++) {
    int row = r + i * 32;
    bf16x8 v = *(const bf16x8*)(xb + ((size_t)(b * 4096 + n0 + row)) * 384 + c0 + c8 * 8);
    unsigned int* trow = (unsigned int*)&t[row][c8 * 8];
#pragma unroll
    for (int j = 0; j < 4; j++) {
      union { unsigned int u; short s[2]; } p;
      p.s[0] = v[j * 2];
      p.s[1] = v[j * 2 + 1];
      trow[j] = p.u;
    }
  }
  __syncthreads();
#pragma unroll
  for (int i = 0; i < 2; i++) {
    int crow = r + i * 32;
    short tb[8];
#pragma unroll
    for (int j = 0; j < 8; j++) tb[j] = t[c8 * 8 + j][crow];
    *(ulonglong2*)(xbT + ((size_t)b * 384 + c0 + crow) * 4096 + n0 + c8 * 8) = *(ulonglong2*)tb;
  }
}

// ---------------------------------------------------------------------------
// weights_prep: merged independent weight-prep work, block-uniform dispatch.
//  blocks [0,576):   wvlT[n][k] = bf16(w_kv_agg[k][384+n])
//  blocks [576,720): bt2 upper half = w_proj^T replicated (LDS transpose)
//  blocks [720,744): qseed = seeds @ w_q_agg * SCALE (1 col/thread, parallel)
// ---------------------------------------------------------------------------
__global__ __launch_bounds__(256) void weights_prep(const float* __restrict__ wkv,
                                                    const float* __restrict__ wproj,
                                                    const float* __restrict__ seeds,
                                                    const float* __restrict__ wqagg,
                                                    __hip_bfloat16* __restrict__ wvlT,
                                                    __hip_bfloat16* __restrict__ bt2,
                                                    float* __restrict__ qseed) {
  __shared__ float shbuf[16 * 385];  // reused per branch
  int bx = blockIdx.x;
  int tid = threadIdx.x;
  if (bx < 576) {
    int idx = bx * 256 + tid;
    if (idx < 384 * 384) {
      int n = idx / 384, k = idx % 384;
      wvlT[idx] = __float2bfloat16(wkv[(size_t)k * 768 + 384 + n]);
    }
  } else if (bx < 720) {
    int bx2 = bx - 576;
    int xt = bx2 % 6, yt = (bx2 / 6) % 6, zb = bx2 / 36;
    float(*t)[65] = (float(*)[65])shbuf;  // [64][65] = 4160 floats < 6160
    int kt = xt * 64, ct = yt * 64;
    int c = tid & 63, r4 = tid >> 6;
#pragma unroll
    for (int i = 0; i < 16; i++) {
      int r = i * 4 + r4;
      t[r][c] = wproj[(size_t)(kt + r) * 384 + ct + c];
    }
    __syncthreads();
    __hip_bfloat16 vals[16];
#pragma unroll
    for (int i = 0; i < 16; i++) vals[i] = __float2bfloat16(t[c][i * 4 + r4]);
    for (int b = zb * 4; b < zb * 4 + 4; b++) {
      __hip_bfloat16* dst = bt2 + (size_t)b * 196608;
#pragma unroll
      for (int i = 0; i < 16; i++) {
        int rr = i * 4 + r4;
        dst[(size_t)(ct + rr) * 512 + kt + c] = vals[i];
      }
    }
  } else {
    int bxq = bx - 720;  // 0..23
    float(*a1)[385] = (float(*)[385])shbuf;
    int cs = bxq * 16;
    for (int idx = tid; idx < 6144; idx += 256) a1[idx / 384][idx % 384] = seeds[idx];
    __syncthreads();
    int m = tid >> 4, cc = tid & 15;
    int col = cs + cc;
    const float* wp = wqagg + col;
    float acc0 = 0.f, acc1 = 0.f, acc2 = 0.f, acc3 = 0.f;
#pragma unroll 4
    for (int k = 0; k < 384; k += 4) {
      acc0 += a1[m][k] * wp[(size_t)k * 384];
      acc1 += a1[m][k + 1] * wp[(size_t)(k + 1) * 384];
      acc2 += a1[m][k + 2] * wp[(size_t)(k + 2) * 384];
      acc3 += a1[m][k + 3] * wp[(size_t)(k + 3) * 384];
    }
    qseed[m * 384 + col] = ((acc0 + acc1) + (acc2 + acc3)) * SCALE;
  }
}

// ---------------------------------------------------------------------------
// fill_wl: wvlT[384*384 + hm*384 + ci] = sum_d w_kv_agg[ci][h*48+d]*qseed[m][h*48+d].
// Grid 192 (1 output/thread).
// ---------------------------------------------------------------------------
__global__ void fill_wl(const float* __restrict__ wkv, const float* __restrict__ qseed,
                        __hip_bfloat16* __restrict__ wvlT) {
  int idx = blockIdx.x * 256 + threadIdx.x;  // 49152
  int hm = idx / 384, ci = idx - hm * 384;
  int h = hm >> 4, m = hm & 15;
  const float* wp = wkv + (size_t)ci * 768 + h * 48;
  const float* qp = qseed + m * 384 + h * 48;
  float acc = 0.f;
#pragma unroll
  for (int d = 0; d < 48; d++) acc += wp[d] * qp[d];
  wvlT[384 * 384 + idx] = __float2bfloat16(acc);
}

// ---------------------------------------------------------------------------
// gemm_anch: anch1 = seeds + gather(pvx @ wvT). A=pvx[2048][384], BT=wvT[384][384].
// Only rows with (row&127)>>4 == col/48 are kept: anch1[b][m][col] = seeds+v.
// Grid (3, 16), XCD-swizzled. Replaces gemm_mfma->outF + anch_fix.
// ---------------------------------------------------------------------------
__global__ __launch_bounds__(256) void gemm_anch(const __hip_bfloat16* __restrict__ A,
                                                 const __hip_bfloat16* __restrict__ BT,
                                                 const float* __restrict__ seeds,
                                                 float* __restrict__ anch1) {
  __shared__ __align__(16) __hip_bfloat16 Asl[128][32];
  __shared__ __align__(16) __hip_bfloat16 Bsl[128][32];
  int nf = xcd_flat(48);
  int bX = nf % 3, bY = nf / 3;
  int tid = threadIdx.x;
  int lane = tid & 63;
  int w = tid >> 6;
  int wr = w >> 1, wc = w & 1;
  int fr = lane & 15, fq = lane >> 4;
  int rowBase = bY * 128, colBase = bX * 128;

  int r1 = tid >> 2, kc1 = tid & 3;
  int r2 = (tid + 256) >> 2;

  char* aB1 = (char*)Asl + (size_t)(w * 64) * 16;
  char* aB2 = (char*)Asl + (size_t)(256 + w * 64) * 16;
  char* bB1 = (char*)Bsl + (size_t)(w * 64) * 16;
  char* bB2 = (char*)Bsl + (size_t)(256 + w * 64) * 16;

  const __hip_bfloat16* a1 = A + (size_t)(rowBase + r1) * 384 + kc1 * 8;
  const __hip_bfloat16* a2 = A + (size_t)(rowBase + r2) * 384 + kc1 * 8;
  const __hip_bfloat16* b1 = BT + (size_t)(colBase + r1) * 384 + kc1 * 8;
  const __hip_bfloat16* b2 = BT + (size_t)(colBase + r2) * 384 + kc1 * 8;

  f32x4 acc[4][4] = {};

  for (int kk = 0; kk < 384; kk += 32) {
    gload16(a1 + kk, aB1);
    gload16(a2 + kk, aB2);
    gload16(b1 + kk, bB1);
    gload16(b2 + kk, bB2);
    __syncthreads();
    bf16x8 af[4], bfv[4];
#pragma unroll
    for (int m = 0; m < 4; m++) af[m] = *(const bf16x8*)&Asl[wr * 64 + m * 16 + fr][fq * 8];
#pragma unroll
    for (int n = 0; n < 4; n++) bfv[n] = *(const bf16x8*)&Bsl[wc * 64 + n * 16 + fr][fq * 8];
#pragma unroll
    for (int m = 0; m < 4; m++)
#pragma unroll
      for (int n = 0; n < 4; n++)
        acc[m][n] = __builtin_amdgcn_mfma_f32_16x16x32_bf16(af[m], bfv[n], acc[m][n], 0, 0, 0);
    __syncthreads();
  }

  // fused anch_fix epilogue: keep only rows whose head group matches col/48
#pragma unroll
  for (int m = 0; m < 4; m++) {
    int row0 = rowBase + wr * 64 + m * 16 + fq * 4;
    int hrow = (row0 & 127) >> 4;  // constant over r (fq*4+r < 16)
#pragma unroll
    for (int n = 0; n < 4; n++) {
      int col = colBase + wc * 64 + n * 16 + fr;
      if (col / 48 == hrow) {
        int b = row0 >> 7;
        int mm = row0 & 15;  // fq*4 base; +r below
        f32x4 v = acc[m][n];
#pragma unroll
        for (int r = 0; r < 4; r++)
          anch1[((size_t)b * 16 + mm + r) * 384 + col] = seeds[(mm + r) * 384 + col] + v[r];
      }
    }
  }
}

// ---------------------------------------------------------------------------
// gemm_out: final projection, K=512, BK=64, XOR-swizzled LDS (chunk ^= row&7).
// out[65536,384] f32 = A2 @ bt2_b^T. Grid (3, 512), XCD-swizzled.
// ---------------------------------------------------------------------------
__global__ __launch_bounds__(256) void gemm_out(const __hip_bfloat16* __restrict__ A,
                                                const __hip_bfloat16* __restrict__ BT,
                                                float* __restrict__ out) {
  __shared__ __align__(16) __hip_bfloat16 Asl[128][64];
  __shared__ __align__(16) __hip_bfloat16 Bsl[128][64];
  int nf = xcd_flat(1536);
  int bX = nf % 3, bY = nf / 3;
  int tid = threadIdx.x;
  int lane = tid & 63;
  int w = tid >> 6;
  int wr = w >> 1, wc = w & 1;
  int fr = lane & 15, fq = lane >> 4;
  int rowBase = bY * 128, colBase = bX * 128;
  const __hip_bfloat16* BTb = BT + (size_t)(rowBase >> 12) * (384 * 512);

  int r0 = tid >> 3, jc = tid & 7;
  int kc = jc ^ (r0 & 7);
  char* aB[4];
  char* bB[4];
  const __hip_bfloat16* a_src[4];
  const __hip_bfloat16* b_src[4];
#pragma unroll
  for (int i = 0; i < 4; i++) {
    aB[i] = (char*)Asl + (size_t)(i * 256 + w * 64) * 16;
    bB[i] = (char*)Bsl + (size_t)(i * 256 + w * 64) * 16;
    a_src[i] = A + (size_t)(rowBase + r0 + i * 32) * 512 + kc * 8;
    b_src[i] = BTb + (size_t)(colBase + r0 + i * 32) * 512 + kc * 8;
  }

  f32x4 acc[4][4] = {};

  for (int kk = 0; kk < 512; kk += 64) {
#pragma unroll
    for (int i = 0; i < 4; i++) {
      gload16(a_src[i] + kk, aB[i]);
      gload16(b_src[i] + kk, bB[i]);
    }
    __syncthreads();
#pragma unroll
    for (int half = 0; half < 2; half++) {
      bf16x8 af[4], bfv[4];
#pragma unroll
      for (int m = 0; m < 4; m++) {
        int row = wr * 64 + m * 16 + fr;
        af[m] = *(const bf16x8*)((char*)Asl + (size_t)row * 128 +
                                 (((fq + 4 * half) ^ (row & 7)) << 4));
      }
#pragma unroll
      for (int n = 0; n < 4; n++) {
        int row = wc * 64 + n * 16 + fr;
        bfv[n] = *(const bf16x8*)((char*)Bsl + (size_t)row * 128 +
                                  (((fq + 4 * half) ^ (row & 7)) << 4));
      }
#pragma unroll
      for (int m = 0; m < 4; m++)
#pragma unroll
        for (int n = 0; n < 4; n++)
          acc[m][n] = __builtin_amdgcn_mfma_f32_16x16x32_bf16(af[m], bfv[n], acc[m][n], 0, 0, 0);
    }
    __syncthreads();
  }

#pragma unroll
  for (int m = 0; m < 4; m++) {
    int row0 = rowBase + wr * 64 + m * 16 + fq * 4;
#pragma unroll
    for (int n = 0; n < 4; n++) {
      int col = colBase + wc * 64 + n * 16 + fr;
      f32x4 v = acc[m][n];
#pragma unroll
      for (int r = 0; r < 4; r++) out[(size_t)(row0 + r) * 384 + col] = v[r];
    }
  }
}

// ---------------------------------------------------------------------------
// gemm_logits: BK=64 swizzled. lgT[b*128+hm][n] = sal·(xb @ Wl^T), transposed
// bf16 write. BT = Wl[128][384]. Grid (512).
// ---------------------------------------------------------------------------
__global__ __launch_bounds__(256) void gemm_logits(const __hip_bfloat16* __restrict__ A,
                                                   const __hip_bfloat16* __restrict__ BT,
                                                   __hip_bfloat16* __restrict__ lgT,
                                                   const float* __restrict__ rowScale) {
  __shared__ __align__(16) __hip_bfloat16 Asl[128][64];
  __shared__ __align__(16) __hip_bfloat16 Bsl[128][64];
  int tid = threadIdx.x;
  int lane = tid & 63;
  int w = tid >> 6;
  int wr = w >> 1, wc = w & 1;
  int fr = lane & 15, fq = lane >> 4;
  int rowBase = blockIdx.x * 128;

  int r0 = tid >> 3, jc = tid & 7;
  int kc = jc ^ (r0 & 7);
  char* aB[4];
  char* bB[4];
  const __hip_bfloat16* a_src[4];
  const __hip_bfloat16* b_src[4];
#pragma unroll
  for (int i = 0; i < 4; i++) {
    aB[i] = (char*)Asl + (size_t)(i * 256 + w * 64) * 16;
    bB[i] = (char*)Bsl + (size_t)(i * 256 + w * 64) * 16;
    a_src[i] = A + (size_t)(rowBase + r0 + i * 32) * 384 + kc * 8;
    b_src[i] = BT + (size_t)(r0 + i * 32) * 384 + kc * 8;
  }

  f32x4 acc[4][4] = {};

  for (int kk = 0; kk < 384; kk += 64) {
#pragma unroll
    for (int i = 0; i < 4; i++) {
      gload16(a_src[i] + kk, aB[i]);
      gload16(b_src[i] + kk, bB[i]);
    }
    __syncthreads();
#pragma unroll
    for (int half = 0; half < 2; half++) {
      bf16x8 af[4], bfv[4];
#pragma unroll
      for (int m = 0; m < 4; m++) {
        int row = wr * 64 + m * 16 + fr;
        af[m] = *(const bf16x8*)((char*)Asl + (size_t)row * 128 +
                                 (((fq + 4 * half) ^ (row & 7)) << 4));
      }
#pragma unroll
      for (int n = 0; n < 4; n++) {
        int row = wc * 64 + n * 16 + fr;
        bfv[n] = *(const bf16x8*)((char*)Bsl + (size_t)row * 128 +
                                  (((fq + 4 * half) ^ (row & 7)) << 4));
      }
#pragma unroll
      for (int m = 0; m < 4; m++)
#pragma unroll
        for (int n = 0; n < 4; n++)
          acc[m][n] = __builtin_amdgcn_mfma_f32_16x16x32_bf16(af[m], bfv[n], acc[m][n], 0, 0, 0);
    }
    __syncthreads();
  }

  float sv[4][4];
#pragma unroll
  for (int m = 0; m < 4; m++)
#pragma unroll
    for (int r = 0; r < 4; r++)
      sv[m][r] = rowScale[rowBase + wr * 64 + m * 16 + fq * 4 + r];

#pragma unroll
  for (int m = 0; m < 4; m++) {
    int row0 = rowBase + wr * 64 + m * 16 + fq * 4;
    int bb = row0 >> 12;
    int n0 = row0 & 4095;
#pragma unroll
    for (int n = 0; n < 4; n++) {
      int col = wc * 64 + n * 16 + fr;  // 0..127 = hm
      __hip_bfloat16 tb[4];
#pragma unroll
      for (int r = 0; r < 4; r++) tb[r] = __float2bfloat16(acc[m][n][r] * sv[m][r]);
      *(unsigned long long*)(lgT + ((size_t)bb * 128 + col) * 4096 + n0) = *(unsigned long long*)tb;
    }
  }
}

// ---------------------------------------------------------------------------
// softmax_rows: Ps[g][n] = softmax_n(lgT[g][n]) * sal[b*4096+n]. bf16 in/out.
// ---------------------------------------------------------------------------
__global__ __launch_bounds__(256) void softmax_rows(const __hip_bfloat16* __restrict__ lgT,
                                                    const float* __restrict__ sal,
                                                    __hip_bfloat16* __restrict__ PT) {
  int g = blockIdx.x;
  const __hip_bfloat16* row = lgT + (size_t)g * 4096;
  int tid = threadIdx.x, wv = tid >> 6, lane = tid & 63;
  __shared__ float redm[4], reds[4];
  float v[16];
  union { ulonglong2 u; __hip_bfloat16 h[8]; } L0, L1;
  L0.u = *(const ulonglong2*)(row + tid * 16);
  L1.u = *(const ulonglong2*)(row + tid * 16 + 8);
#pragma unroll
  for (int i = 0; i < 8; i++) {
    v[i] = __bfloat162float(L0.h[i]);
    v[8 + i] = __bfloat162float(L1.h[i]);
  }
  float mx = v[0];
#pragma unroll
  for (int i = 1; i < 16; i++) mx = fmaxf(mx, v[i]);
#pragma unroll
  for (int off = 1; off < 64; off <<= 1) mx = fmaxf(mx, __shfl_xor(mx, off));
  if (lane == 0) redm[wv] = mx;
  __syncthreads();
  mx = fmaxf(fmaxf(redm[0], redm[1]), fmaxf(redm[2], redm[3]));
  float s = 0.f;
#pragma unroll
  for (int i = 0; i < 16; i++) {
    v[i] = __expf(v[i] - mx);
    s += v[i];
  }
#pragma unroll
  for (int off = 1; off < 64; off <<= 1) s += __shfl_xor(s, off);
  if (lane == 0) reds[wv] = s;
  __syncthreads();
  s = (reds[0] + reds[1]) + (reds[2] + reds[3]);
  float inv = 1.f / s;
  const float* sp = sal + (size_t)(g >> 7) * 4096 + tid * 16;
  float salv[16];
#pragma unroll
  for (int i = 0; i < 4; i++) {
    float4 q = *(const float4*)(sp + i * 4);
    salv[i * 4] = q.x; salv[i * 4 + 1] = q.y; salv[i * 4 + 2] = q.z; salv[i * 4 + 3] = q.w;
  }
  __hip_bfloat16 tb[16];
#pragma unroll
  for (int i = 0; i < 16; i++) tb[i] = __float2bfloat16(v[i] * inv * salv[i]);
  __hip_bfloat16* op = PT + (size_t)g * 4096 + tid * 16;
  *(ulonglong2*)op = *(ulonglong2*)tb;
  *(ulonglong2*)(op + 8) = *(ulonglong2*)(tb + 8);
}

// ---------------------------------------------------------------------------
// gemm_pvx: BK=64 swizzled split-K PV: pbuf[z][g][c] = Ps[g,zslice] @ xbT_b^T.
// Grid (3, 16, 4), XCD-swizzled.
// ---------------------------------------------------------------------------
__global__ __launch_bounds__(256) void gemm_pvx(const __hip_bfloat16* __restrict__ PT,
                                                const __hip_bfloat16* __restrict__ xbT,
                                                float* __restrict__ pbuf) {
  __shared__ __align__(16) __hip_bfloat16 Asl[128][64];
  __shared__ __align__(16) __hip_bfloat16 Bsl[128][64];
  int nf = xcd_flat(192);
  int bX = nf % 3, bY = (nf / 3) & 15, kz = nf / 48;
  int tid = threadIdx.x;
  int lane = tid & 63;
  int w = tid >> 6;
  int wr = w >> 1, wc = w & 1;
  int fr = lane & 15, fq = lane >> 4;
  int rowBase = bY * 128, colBase = bX * 128;
  const __hip_bfloat16* BTb = xbT + (size_t)bY * 384 * 4096;

  int r0 = tid >> 3, jc = tid & 7;
  int kc = jc ^ (r0 & 7);
  char* aB[4];
  char* bB[4];
  const __hip_bfloat16* a_src[4];
  const __hip_bfloat16* b_src[4];
#pragma unroll
  for (int i = 0; i < 4; i++) {
    aB[i] = (char*)Asl + (size_t)(i * 256 + w * 64) * 16;
    bB[i] = (char*)Bsl + (size_t)(i * 256 + w * 64) * 16;
    a_src[i] = PT + (size_t)(rowBase + r0 + i * 32) * 4096 + kz * 1024 + kc * 8;
    b_src[i] = BTb + (size_t)(colBase + r0 + i * 32) * 4096 + kz * 1024 + kc * 8;
  }

  f32x4 acc[4][4] = {};

  for (int kk = 0; kk < 1024; kk += 64) {
#pragma unroll
    for (int i = 0; i < 4; i++) {
      gload16(a_src[i] + kk, aB[i]);
      gload16(b_src[i] + kk, bB[i]);
    }
    __syncthreads();
#pragma unroll
    for (int half = 0; half < 2; half++) {
      bf16x8 af[4], bfv[4];
#pragma unroll
      for (int m = 0; m < 4; m++) {
        int row = wr * 64 + m * 16 + fr;
        af[m] = *(const bf16x8*)((char*)Asl + (size_t)row * 128 +
                                 (((fq + 4 * half) ^ (row & 7)) << 4));
      }
#pragma unroll
      for (int n = 0; n < 4; n++) {
        int row = wc * 64 + n * 16 + fr;
        bfv[n] = *(const bf16x8*)((char*)Bsl + (size_t)row * 128 +
                                  (((fq + 4 * half) ^ (row & 7)) << 4));
      }
#pragma unroll
      for (int m = 0; m < 4; m++)
#pragma unroll
        for (int n = 0; n < 4; n++)
          acc[m][n] = __builtin_amdgcn_mfma_f32_16x16x32_bf16(af[m], bfv[n], acc[m][n], 0, 0, 0);
    }
    __syncthreads();
  }

  float* outz = pbuf + (size_t)kz * 786432;
#pragma unroll
  for (int m = 0; m < 4; m++) {
    int row0 = rowBase + wr * 64 + m * 16 + fq * 4;
#pragma unroll
    for (int n = 0; n < 4; n++) {
      int col = colBase + wc * 64 + n * 16 + fr;
      f32x4 v = acc[m][n];
#pragma unroll
      for (int r = 0; r < 4; r++) outz[(size_t)(row0 + r) * 384 + col] = v[r];
    }
  }
}

// ---------------------------------------------------------------------------
// reduce_z: pvx[i] = bf16(sum_z pbuf[z][i]), 4 elems/thread. Grid 768.
// ---------------------------------------------------------------------------
__global__ __launch_bounds__(256) void reduce_z(const float* __restrict__ pbuf,
                                                __hip_bfloat16* __restrict__ pvx) {
  int i4 = (blockIdx.x * 256 + threadIdx.x) * 4;
  float4 s = *(const float4*)(pbuf + i4);
#pragma unroll
  for (int z = 1; z < 4; z++) {
    float4 t = *(const float4*)(pbuf + (size_t)z * 786432 + i4);
    s.x += t.x; s.y += t.y; s.z += t.z; s.w += t.w;
  }
  __hip_bfloat16 tb[4] = {__float2bfloat16(s.x), __float2bfloat16(s.y),
                          __float2bfloat16(s.z), __float2bfloat16(s.w)};
  *(unsigned long long*)(pvx + i4) = *(unsigned long long*)tb;
}

// ---------------------------------------------------------------------------
// kvfold: fused kv_bcast projection + per-batch folded-weight fills.
// Grid (16, 16): x<8 -> wpbT (h=x, k-half, SCALE folded); x>=8 -> bt2 v-half.
// ---------------------------------------------------------------------------
__global__ __launch_bounds__(256) void kvfold(const float* __restrict__ anch2,
                                              const float* __restrict__ wkvb,
                                              const float* __restrict__ wq,
                                              const float* __restrict__ wproj,
                                              __hip_bfloat16* __restrict__ wpbT,
                                              __hip_bfloat16* __restrict__ bt2) {
  int b = blockIdx.y;
  int tid = threadIdx.x;
  __shared__ float a2s[16][385];
  __shared__ float stage[16][48];
  __shared__ __hip_bfloat16 obuf[16][264];
  bool isK = blockIdx.x < 8;
  int h = isK ? blockIdx.x : blockIdx.x - 8;
  int colBase = (isK ? 0 : 384) + h * 48;
  float scale = isK ? SCALE : 1.f;
  for (int idx = tid; idx < 6144; idx += 256) a2s[idx / 384][idx % 384] = anch2[b * 6144 + idx];
  __syncthreads();
  for (int o = tid; o < 768; o += 256) {
    int m = o / 48, d = o - m * 48;
    const float* wp = wkvb + colBase + d;
    float acc0 = 0.f, acc1 = 0.f, acc2 = 0.f, acc3 = 0.f;
#pragma unroll 4
    for (int k = 0; k < 384; k += 4) {
      acc0 += a2s[m][k] * wp[(size_t)k * 768];
      acc1 += a2s[m][k + 1] * wp[(size_t)(k + 1) * 768];
      acc2 += a2s[m][k + 2] * wp[(size_t)(k + 2) * 768];
      acc3 += a2s[m][k + 3] * wp[(size_t)(k + 3) * 768];
    }
    stage[m][d] = ((acc0 + acc1) + (acc2 + acc3)) * scale;
  }
  __syncthreads();
  if (isK) {
    for (int kbase = 0; kbase < 384; kbase += 256) {
      int chunk = (kbase == 0) ? 256 : 128;
      if (tid < chunk) {
        int k = kbase + tid;
        const float4* wp = (const float4*)(wq + (size_t)k * 384 + h * 48);
        float acc[16] = {};
#pragma unroll
        for (int dq = 0; dq < 12; dq++) {
          float4 wv = wp[dq];
#pragma unroll
          for (int m = 0; m < 16; m++)
            acc[m] += stage[m][dq * 4] * wv.x + stage[m][dq * 4 + 1] * wv.y +
                      stage[m][dq * 4 + 2] * wv.z + stage[m][dq * 4 + 3] * wv.w;
        }
#pragma unroll
        for (int m = 0; m < 16; m++) obuf[m][tid] = __float2bfloat16(acc[m]);
      }
      __syncthreads();
      for (int widx = tid; widx < 16 * chunk; widx += 256) {
        int m = widx / chunk, kk = widx - m * chunk;
        wpbT[(size_t)b * 49152 + (size_t)(h * 16 + m) * 384 + kbase + kk] = obuf[m][kk];
      }
      __syncthreads();
    }
  } else {
    for (int cp = tid; cp < 384; cp += 256) {
      float acc[16] = {};
      for (int d = 0; d < 48; d++) {
        float wv = wproj[(size_t)(h * 48 + d) * 384 + cp];
#pragma unroll
        for (int m = 0; m < 16; m++) acc[m] += stage[m][d] * wv;
      }
      __hip_bfloat16 tb[16];
#pragma unroll
      for (int m = 0; m < 16; m++) tb[m] = __float2bfloat16(acc[m]);
      __hip_bfloat16* dst = bt2 + (size_t)b * 196608 + (size_t)cp * 512 + 384 + h * 16;
      *(ulonglong2*)dst = *(ulonglong2*)tb;
      *(ulonglong2*)(dst + 8) = *(ulonglong2*)(tb + 8);
    }
  }
}

// ---------------------------------------------------------------------------
// pgemm: BK=64 swizzled. P = softmax_per_head(xb @ W_pbT_b^T) -> A2[:,384+hm].
// Grid (512).
// ---------------------------------------------------------------------------
__global__ __launch_bounds__(256) void pgemm(const __hip_bfloat16* __restrict__ A,
                                             const __hip_bfloat16* __restrict__ wpbT,
                                             __hip_bfloat16* __restrict__ A2) {
  __shared__ __align__(16) __hip_bfloat16 Asl[128][64];
  __shared__ __align__(16) __hip_bfloat16 Bsl[128][64];
  int tid = threadIdx.x;
  int lane = tid & 63;
  int w = tid >> 6;
  int wr = w >> 1, wc = w & 1;
  int fr = lane & 15, fq = lane >> 4;
  int rowBase = blockIdx.x * 128;
  const __hip_bfloat16* BTb = wpbT + (size_t)(rowBase >> 12) * (128 * 384);

  int r0 = tid >> 3, jc = tid & 7;
  int kc = jc ^ (r0 & 7);
  char* aB[4];
  char* bB[4];
  const __hip_bfloat16* a_src[4];
  const __hip_bfloat16* b_src[4];
#pragma unroll
  for (int i = 0; i < 4; i++) {
    aB[i] = (char*)Asl + (size_t)(i * 256 + w * 64) * 16;
    bB[i] = (char*)Bsl + (size_t)(i * 256 + w * 64) * 16;
    a_src[i] = A + (size_t)(rowBase + r0 + i * 32) * 384 + kc * 8;
    b_src[i] = BTb + (size_t)(r0 + i * 32) * 384 + kc * 8;
  }

  f32x4 acc[4][4] = {};

  for (int kk = 0; kk < 384; kk += 64) {
#pragma unroll
    for (int i = 0; i < 4; i++) {
      gload16(a_src[i] + kk, aB[i]);
      gload16(b_src[i] + kk, bB[i]);
    }
    __syncthreads();
#pragma unroll
    for (int half = 0; half < 2; half++) {
      bf16x8 af[4], bfv[4];
#pragma unroll
      for (int m = 0; m < 4; m++) {
        int row = wr * 64 + m * 16 + fr;
        af[m] = *(const bf16x8*)((char*)Asl + (size_t)row * 128 +
                                 (((fq + 4 * half) ^ (row & 7)) << 4));
      }
#pragma unroll
      for (int n = 0; n < 4; n++) {
        int row = wc * 64 + n * 16 + fr;
        bfv[n] = *(const bf16x8*)((char*)Bsl + (size_t)row * 128 +
                                  (((fq + 4 * half) ^ (row & 7)) << 4));
      }
#pragma unroll
      for (int m = 0; m < 4; m++)
#pragma unroll
        for (int n = 0; n < 4; n++)
          acc[m][n] = __builtin_amdgcn_mfma_f32_16x16x32_bf16(af[m], bfv[n], acc[m][n], 0, 0, 0);
    }
    __syncthreads();
  }

  // epilogue: per (row, head) softmax over the 16-lane fr group -> A2[:,384+col]
#pragma unroll
  for (int m = 0; m < 4; m++) {
    int row0 = rowBase + wr * 64 + m * 16 + fq * 4;
#pragma unroll
    for (int n = 0; n < 4; n++) {
      int col = wc * 64 + n * 16 + fr;
      f32x4 v = acc[m][n];
      f32x4 mx = v;
#pragma unroll
      for (int off = 1; off < 16; off <<= 1)
#pragma unroll
        for (int r = 0; r < 4; r++) mx[r] = fmaxf(mx[r], __shfl_xor(mx[r], off));
      f32x4 e;
#pragma unroll
      for (int r = 0; r < 4; r++) e[r] = __expf(v[r] - mx[r]);
      f32x4 s = e;
#pragma unroll
      for (int off = 1; off < 16; off <<= 1)
#pragma unroll
        for (int r = 0; r < 4; r++) s[r] += __shfl_xor(s[r], off);
#pragma unroll
      for (int r = 0; r < 4; r++)
        A2[(size_t)(row0 + r) * 512 + 384 + col] = __float2bfloat16(e[r] / s[r]);
    }
  }
}

// ---------------------------------------------------------------------------
// dwconv3: depthwise 3x3 conv with x-walking register-rotated tap columns.
// ---------------------------------------------------------------------------
__global__ __launch_bounds__(256) void dwconv3(const __hip_bfloat16* __restrict__ xb,
                                               const float* __restrict__ dwk,
                                               __hip_bfloat16* __restrict__ A2) {
  int b = blockIdx.y;
  int y = blockIdx.x;  // 0..63
  int w = threadIdx.x >> 6, lane = threadIdx.x & 63;
  int c0 = lane * 6;
  int x0 = w * 16;
  float kw[9][6];
#pragma unroll
  for (int ki = 0; ki < 9; ki++)
#pragma unroll
    for (int i = 0; i < 6; i++) kw[ki][i] = dwk[(c0 + i) * 9 + ki];

  const __hip_bfloat16* base = xb + ((size_t)(b * 4096 + y * 64)) * 384 + c0;
  bool yv[3];
#pragma unroll
  for (int t = 0; t < 3; t++) {
    int yy = y + t - 1;
    yv[t] = (yy >= 0 && yy < 64);
  }

  float colL[3][6], colC[3][6], colR[3][6];
  auto loadcol = [&](float (&dst)[3][6], int x) {
#pragma unroll
    for (int t = 0; t < 3; t++) {
      if (yv[t]) {
        const __hip_bfloat16* p = base + ((size_t)(t - 1) * 64 + x) * 384;
#pragma unroll
        for (int i = 0; i < 6; i++) dst[t][i] = __bfloat162float(p[i]);
      } else {
#pragma unroll
        for (int i = 0; i < 6; i++) dst[t][i] = 0.f;
      }
    }
  };

  if (x0 == 0) {
#pragma unroll
    for (int t = 0; t < 3; t++)
#pragma unroll
      for (int i = 0; i < 6; i++) colL[t][i] = 0.f;
  } else {
    loadcol(colL, x0 - 1);
  }
  loadcol(colC, x0);

  for (int step = 0; step < 16; step++) {
    int x = x0 + step;
    if (x + 1 < 64) {
      loadcol(colR, x + 1);
    } else {
#pragma unroll
      for (int t = 0; t < 3; t++)
#pragma unroll
        for (int i = 0; i < 6; i++) colR[t][i] = 0.f;
    }
    float acc[6];
#pragma unroll
    for (int i = 0; i < 6; i++) {
      float a = 0.f;
#pragma unroll
      for (int t = 0; t < 3; t++)
        a += colL[t][i] * kw[t * 3 + 0][i] + colC[t][i] * kw[t * 3 + 1][i] +
             colR[t][i] * kw[t * 3 + 2][i];
      acc[i] = a;
    }
    __hip_bfloat16 tb[6];
#pragma unroll
    for (int i = 0; i < 6; i++) tb[i] = __float2bfloat16(acc[i]);
    __hip_bfloat16* gp = A2 + ((size_t)(b * 4096 + y * 64 + x)) * 512 + c0;
    *(unsigned int*)(gp) = *(unsigned int*)(tb);
    *(unsigned int*)(gp + 2) = *(unsigned int*)(tb + 2);
    *(unsigned int*)(gp + 4) = *(unsigned int*)(tb + 4);
#pragma unroll
    for (int t = 0; t < 3; t++)
#pragma unroll
      for (int i = 0; i < 6; i++) {
        colL[t][i] = colC[t][i];
        colC[t][i] = colR[t][i];
      }
  }
}

// ---------------------------------------------------------------------------
// anchor_proj_qkv: fused q_self (x<24) + kv_self (x>=24) projections.
// ---------------------------------------------------------------------------
__global__ __launch_bounds__(256) void anchor_proj_qkv(const float* __restrict__ A,
                                                       const float* __restrict__ Wq,
                                                       const float* __restrict__ Wkv,
                                                       float* __restrict__ q_out,
                                                       float* __restrict__ kv_out) {
  bool isQ = blockIdx.x < 24;
  int bx = isQ ? blockIdx.x : blockIdx.x - 24;
  const float* W = isQ ? Wq : Wkv;
  float* outp = isQ ? q_out : kv_out;
  int wstride = isQ ? 384 : 768;
  float scale = isQ ? SCALE : 1.f;
  int cs = bx * 16;
  int b = blockIdx.y;
  __shared__ float a1[16][385];
  int tid = threadIdx.x;
  for (int idx = tid; idx < 6144; idx += 256) a1[idx / 384][idx % 384] = A[b * 6144 + idx];
  __syncthreads();
  int m = tid >> 4, cc = tid & 15;
  int col = cs + cc;
  const float* wp = W + col;
  float acc0 = 0.f, acc1 = 0.f, acc2 = 0.f, acc3 = 0.f;
#pragma unroll 4
  for (int k = 0; k < 384; k += 4) {
    acc0 += a1[m][k] * wp[(size_t)k * wstride];
    acc1 += a1[m][k + 1] * wp[(size_t)(k + 1) * wstride];
    acc2 += a1[m][k + 2] * wp[(size_t)(k + 2) * wstride];
    acc3 += a1[m][k + 3] * wp[(size_t)(k + 3) * wstride];
  }
  float acc = ((acc0 + acc1) + (acc2 + acc3)) * scale;
  outp[((size_t)b * 16 + m) * wstride + col] = acc;
}

// ---------------------------------------------------------------------------
// Self attention on anchors (16x16, per (b,h)); anchors2 = anchors1 + out.
// ---------------------------------------------------------------------------
__global__ void self_attn(const float* __restrict__ qsf, const float* __restrict__ kvs,
                          const float* __restrict__ anch1, float* __restrict__ anch2) {
  int h = blockIdx.x & 7, b = blockIdx.x >> 3;
  __shared__ float qs[16][48], ks[16][48], vs[16][48], p[16][17];
  int tid = threadIdx.x;
  for (int idx = tid; idx < 768; idx += 256) {
    int m = idx / 48, d = idx % 48;
    qs[m][d] = qsf[(b * 16 + m) * 384 + h * 48 + d];
    ks[m][d] = kvs[(b * 16 + m) * 768 + h * 48 + d];
    vs[m][d] = kvs[(b * 16 + m) * 768 + 384 + h * 48 + d];
  }
  __syncthreads();
  {
    int mq = tid >> 4, mk = tid & 15;
    float acc = 0.f;
    for (int d = 0; d < 48; d++) acc += qs[mq][d] * ks[mk][d];
    p[mq][mk] = acc;
  }
  __syncthreads();
  if (tid < 16) {
    float mx = -1e30f;
    for (int mk = 0; mk < 16; mk++) mx = fmaxf(mx, p[tid][mk]);
    float sum = 0.f;
    for (int mk = 0; mk < 16; mk++) {
      float e = __expf(p[tid][mk] - mx);
      p[tid][mk] = e;
      sum += e;
    }
    float inv = 1.f / sum;
    for (int mk = 0; mk < 16; mk++) p[tid][mk] *= inv;
  }
  __syncthreads();
  for (int idx = tid; idx < 768; idx += 256) {
    int m = idx / 48, d = idx % 48;
    float acc = 0.f;
    for (int mk = 0; mk < 16; mk++) acc += p[m][mk] * vs[mk][d];
    int c = h * 48 + d;
    anch2[(b * 16 + m) * 384 + c] = anch1[(b * 16 + m) * 384 + c] + acc;
  }
}

// ---------------------------------------------------------------------------
extern "C" void kernel_launch(void* const* d_in, const int* in_sizes, int n_in,
                              void* d_out, int out_size, void* d_ws, size_t ws_size,
                              hipStream_t stream) {
  (void)in_sizes; (void)n_in; (void)out_size; (void)ws_size;
  const float* x = (const float*)d_in[0];
  const float* wsal = (const float*)d_in[3];
  const float* bsal = (const float*)d_in[4];
  const float* seeds = (const float*)d_in[5];
  const float* w_q_agg = (const float*)d_in[6];
  const float* w_kv_agg = (const float*)d_in[7];
  const float* w_q_self = (const float*)d_in[8];
  const float* w_kv_self = (const float*)d_in[9];
  const float* w_q_bcast = (const float*)d_in[10];
  const float* w_kv_bcast = (const float*)d_in[11];
  const float* dwk = (const float*)d_in[12];
  const float* w_proj = (const float*)d_in[13];
  float* out = (float*)d_out;

  char* ws = (char*)d_ws;
  size_t off = 0;
  auto take = [&](size_t bytes) -> void* {
    void* p = ws + off;
    off += (bytes + 255) & ~(size_t)255;
    return p;
  };
  __hip_bfloat16* xb = (__hip_bfloat16*)take(50331648);   // bf16(x)
  __hip_bfloat16* xbT = (__hip_bfloat16*)take(50331648);  // [16][384][4096] bf16
  char* R = (char*)take(67108864);                        // logitsT(16M) -> pbuf(12.6M) -> A2(64M)
  __hip_bfloat16* PT = (__hip_bfloat16*)take(16777216);   // [2048][4096] bf16 (Ps, sal-folded)
  __hip_bfloat16* pvx = (__hip_bfloat16*)take(1572864);   // [2048][384] bf16
  float* qseed = (float*)take(24576);
  float* sal = (float*)take(262144);
  float* anch1 = (float*)take(393216);
  float* anch2 = (float*)take(393216);
  float* q_self = (float*)take(393216);
  float* kv_self = (float*)take(786432);
  __hip_bfloat16* wvlT = (__hip_bfloat16*)take(393216);   // [512][384]: wvT ++ Wl
  __hip_bfloat16* wpbT = (__hip_bfloat16*)take(1572864);  // [16][128][384] bf16
  __hip_bfloat16* bt2 = (__hip_bfloat16*)take(6291456);   // [16][384][512] bf16
  __hip_bfloat16* logitsT = (__hip_bfloat16*)R;
  float* pbuf = (float*)R;                  // alias: logits dead after softmax_rows
  __hip_bfloat16* A2 = (__hip_bfloat16*)R;  // alias: pbuf dead after reduce_z

  // 1) xb + saliency; xbT (separate high-occupancy passes)
  prep<<<16384, 256, 0, stream>>>(x, wsal, bsal, xb, sal);
  xtrans<<<dim3(64, 6, 16), 256, 0, stream>>>(xb, xbT);
  // 2) merged weight prep: wvT + bt2 upper half + qseed (parallel)
  weights_prep<<<744, 256, 0, stream>>>(w_kv_agg, w_proj, seeds, w_q_agg, wvlT, bt2, qseed);
  fill_wl<<<192, 256, 0, stream>>>(w_kv_agg, qseed, wvlT);
  // 3) logits = sal·(xb @ Wl^T), transposed bf16 (BK=64 swizzled)
  gemm_logits<<<512, 256, 0, stream>>>(xb, wvlT + 384 * 384, logitsT, sal);
  // 4) Ps = softmax ⊙ sal; pbuf = Ps @ xbT^T (split-K 4, BK=64 swizzled)
  softmax_rows<<<2048, 256, 0, stream>>>(logitsT, sal, PT);
  gemm_pvx<<<dim3(3, 16, 4), 256, 0, stream>>>(PT, xbT, pbuf);
  reduce_z<<<768, 256, 0, stream>>>(pbuf, pvx);
  // 5) anchors1 = seeds + gather(pvx @ wv)  (fused epilogue, outF eliminated)
  gemm_anch<<<dim3(3, 16), 256, 0, stream>>>(pvx, wvlT, seeds, anch1);
  // 6) anchor self-attention -> anchors2
  anchor_proj_qkv<<<dim3(72, 16), 256, 0, stream>>>(anch1, w_q_self, w_kv_self, q_self, kv_self);
  self_attn<<<128, 256, 0, stream>>>(q_self, kv_self, anch1, anch2);
  // 7) kv_bcast projection fused with per-batch folded-weight fills
  kvfold<<<dim3(16, 16), 256, 0, stream>>>(anch2, w_kv_bcast, w_q_bcast, w_proj, wpbT, bt2);
  // 8) A2 = [dwconv(xb) | softmax(xb @ W_pbT_b)]  (pbuf dead -> A2, BK=64)
  pgemm<<<512, 256, 0, stream>>>(xb, wpbT, A2);
  dwconv3<<<dim3(64, 16), 256, 0, stream>>>(xb, dwk, A2);
  // 9) out = A2 @ BT2_b   (K=512, BK=64 swizzled, f32 out)
  gemm_out<<<dim3(3, 512), 256, 0, stream>>>(A2, bt2, out);
}